// Round 1
// baseline (381.560 us; speedup 1.0000x reference)
//
#include <hip/hip_runtime.h>
#include <math.h>
#include <stdint.h>

#define NTOK 8192
#define DIM  512
#define NEXP 8
#define HIDN 512
#define BM 128
#define BN 128
#define BK 32
#define MAXRB 72              // ceil((8192 + 8*127)/128)
#define SLOTS (MAXRB*BM)      // 9216

typedef _Float16 f16;
typedef __attribute__((ext_vector_type(4))) _Float16 f16x4;
typedef __attribute__((ext_vector_type(8))) _Float16 f16x8;
typedef __attribute__((ext_vector_type(4))) float    f32x4;

__device__ __forceinline__ void gl2lds16(const void* g, void* l) {
  __builtin_amdgcn_global_load_lds(
      (const __attribute__((address_space(1))) unsigned int*)(g),
      (__attribute__((address_space(3))) unsigned int*)(l), 16, 0, 0);
}

// ---------- converts ----------
__global__ void k_conv_x(const float* __restrict__ x, f16* __restrict__ xh) {
  int i4 = (blockIdx.x * 256 + threadIdx.x) * 4;
  float4 v = *(const float4*)(x + i4);
  f16x4 o; o.x = (_Float16)v.x; o.y = (_Float16)v.y; o.z = (_Float16)v.z; o.w = (_Float16)v.w;
  *(f16x4*)(xh + i4) = o;
}

// W [E][K][N] fp32 -> Wt [E][N][K] f16
__global__ void k_transpose_cast(const float* __restrict__ W, f16* __restrict__ Wt) {
  __shared__ float t[32][33];
  int e = blockIdx.z;
  int k0 = blockIdx.x * 32, n0 = blockIdx.y * 32;
  const float* src = W + (size_t)e * DIM * DIM;
  f16* dst = Wt + (size_t)e * DIM * DIM;
  int tx = threadIdx.x & 31, ty = threadIdx.x >> 5;
  for (int r = ty; r < 32; r += 8) t[r][tx] = src[(size_t)(k0 + r) * DIM + n0 + tx];
  __syncthreads();
  for (int r = ty; r < 32; r += 8) dst[(size_t)(n0 + r) * DIM + k0 + tx] = (f16)t[tx][r];
}

// ---------- fp64 gate fold: Wg = Wv @ (Wo @ gate_W), bg folded ----------
__global__ void k_foldA(const float* __restrict__ Wo, const float* __restrict__ gW,
                        double* __restrict__ G1) {
  int out = blockIdx.x * 4 + (threadIdx.x >> 6);
  int lane = threadIdx.x & 63;
  int d = out >> 3, e = out & 7;
  double acc = 0.0;
#pragma unroll
  for (int j = 0; j < 8; j++) {
    int k = j * 64 + lane;
    acc += (double)Wo[d * DIM + k] * (double)gW[k * NEXP + e];
  }
#pragma unroll
  for (int off = 32; off; off >>= 1) acc += __shfl_xor(acc, off, 64);
  if (lane == 0) G1[out] = acc;
}

__global__ void k_foldB(const float* __restrict__ Wv, const double* __restrict__ G1,
                        double* __restrict__ Wg) {
  int out = blockIdx.x * 4 + (threadIdx.x >> 6);
  int lane = threadIdx.x & 63;
  int d = out >> 3, e = out & 7;
  double acc = 0.0;
#pragma unroll
  for (int j = 0; j < 8; j++) {
    int k = j * 64 + lane;
    acc += (double)Wv[d * DIM + k] * G1[k * NEXP + e];
  }
#pragma unroll
  for (int off = 32; off; off >>= 1) acc += __shfl_xor(acc, off, 64);
  if (lane == 0) Wg[out] = acc;
}

__global__ void k_foldbg(const double* __restrict__ G1, const float* __restrict__ bv,
                         const float* __restrict__ bo, const float* __restrict__ gW,
                         const float* __restrict__ gb, double* __restrict__ bg) {
  int lane = threadIdx.x & 63, w = threadIdx.x >> 6;
  for (int e = w; e < NEXP; e += 4) {
    double acc = 0.0;
#pragma unroll
    for (int j = 0; j < 8; j++) {
      int d = j * 64 + lane;
      acc += (double)bv[d] * G1[d * NEXP + e] + (double)bo[d] * (double)gW[d * NEXP + e];
    }
#pragma unroll
    for (int off = 32; off; off >>= 1) acc += __shfl_xor(acc, off, 64);
    if (lane == 0) bg[e] = acc + (double)gb[e];
  }
}

// ---------- gate: logits(fp64), softmax, top-2, counts ----------
__global__ void k_gate(const float* __restrict__ q, const double* __restrict__ Wg,
                       const double* __restrict__ bg, float* __restrict__ gp_out,
                       int* __restrict__ e1a, int* __restrict__ e2a,
                       float* __restrict__ w1a, float* __restrict__ w2a,
                       int* __restrict__ counts) {
  int tok = blockIdx.x * 4 + (threadIdx.x >> 6);
  int lane = threadIdx.x & 63;
  const float* qr = q + (size_t)tok * DIM;
  double acc[8] = {0, 0, 0, 0, 0, 0, 0, 0};
#pragma unroll
  for (int j = 0; j < 8; j++) {
    double qv = (double)qr[lane * 8 + j];
    const double* wr = Wg + (size_t)(lane * 8 + j) * NEXP;
#pragma unroll
    for (int e = 0; e < 8; e++) acc[e] += qv * wr[e];
  }
#pragma unroll
  for (int off = 32; off; off >>= 1)
#pragma unroll
    for (int e = 0; e < 8; e++) acc[e] += __shfl_xor(acc[e], off, 64);
  if (lane == 0) {
    double l[8], p[8];
    double m = -1e300;
#pragma unroll
    for (int e = 0; e < 8; e++) { l[e] = acc[e] + bg[e]; m = fmax(m, l[e]); }
    double s = 0.0;
#pragma unroll
    for (int e = 0; e < 8; e++) { p[e] = exp(l[e] - m); s += p[e]; }
    double inv = 1.0 / s;
#pragma unroll
    for (int e = 0; e < 8; e++) { p[e] *= inv; gp_out[(size_t)tok * 8 + e] = (float)p[e]; }
    int i1 = 0;
#pragma unroll
    for (int e = 1; e < 8; e++) if (p[e] > p[i1]) i1 = e;
    int i2 = (i1 == 0) ? 1 : 0;
#pragma unroll
    for (int e = 0; e < 8; e++) if (e != i1 && p[e] > p[i2]) i2 = e;
    double ev = exp(p[i2] - p[i1]);
    double w1 = 1.0 / (1.0 + ev), w2 = ev / (1.0 + ev);
    e1a[tok] = i1; e2a[tok] = i2;
    w1a[tok] = (float)w1; w2a[tok] = (float)w2;
    atomicAdd(&counts[i1], 1);
    atomicAdd(&counts[8 + i2], 1);
  }
}

__global__ void k_scan(const int* __restrict__ counts, int* __restrict__ aoff,
                       int* __restrict__ cursors) {
  if (threadIdx.x == 0) {
    for (int k = 0; k < 2; k++) {
      int off = 0;
      for (int e = 0; e < NEXP; e++) {
        aoff[k * 9 + e] = off;
        off += (counts[k * 8 + e] + BM - 1) / BM * BM;
      }
      aoff[k * 9 + 8] = off;
    }
    for (int i = 0; i < 16; i++) cursors[i] = 0;
  }
}

__global__ void k_scatter(const int* __restrict__ e1a, const int* __restrict__ e2a,
                          const float* __restrict__ w1a, const float* __restrict__ w2a,
                          const int* __restrict__ aoff, int* __restrict__ cursors,
                          int* __restrict__ toks, float* __restrict__ wsl) {
  int n = blockIdx.x * 256 + threadIdx.x;
  int e1 = e1a[n];
  int pos = atomicAdd(&cursors[e1], 1);
  int slot = aoff[e1] + pos;
  toks[slot] = n; wsl[slot] = w1a[n];
  int e2 = e2a[n];
  pos = atomicAdd(&cursors[8 + e2], 1);
  slot = SLOTS + aoff[9 + e2] + pos;
  toks[slot] = n; wsl[slot] = w2a[n];
}

// ---------- expert GEMM: MODE 0 = layer1 (x->H, relu), 1 = layer2 k=0 (y=),
// 2 = layer2 k=1 (y+=) ----------
template <int MODE>
__global__ __launch_bounds__(256) void k_expert(
    const f16* __restrict__ Asrc, const f16* __restrict__ Wt,
    const float* __restrict__ bias, const int* __restrict__ toks,
    const float* __restrict__ wsl, const int* __restrict__ aoff,
    const int* __restrict__ counts, f16* __restrict__ Hout,
    float* __restrict__ y, int kpass) {
  const int klist = (MODE == 0) ? blockIdx.z : kpass;
  const int* ao = aoff + klist * 9;
  const int slot0 = blockIdx.x * BM;
  if (slot0 >= ao[8]) return;
  int e = 0;
#pragma unroll
  for (int t = 1; t <= 7; t++) if (slot0 >= ao[t]) e = t;

  const int n0 = blockIdx.y * BN;
  const int tid = threadIdx.x, lane = tid & 63, wid = tid >> 6;

  __shared__ __align__(16) f16 As[BM * BK];
  __shared__ __align__(16) f16 Bs[BN * BK];

  const int srow = wid * 16 + (lane >> 2);
  const int scol = (lane & 3) * 8;
  const f16* arow[2];
  const f16* brow[2];
  f16* alds[2];
  f16* blds[2];
#pragma unroll
  for (int rnd = 0; rnd < 2; rnd++) {
    int r = srow + rnd * 64;
    if (MODE == 0) {
      int tk = toks[klist * SLOTS + slot0 + r];
      arow[rnd] = Asrc + (size_t)tk * DIM + scol;
    } else {
      arow[rnd] = Asrc + (size_t)(klist * SLOTS + slot0 + r) * HIDN + scol;
    }
    brow[rnd] = Wt + ((size_t)e * DIM + n0 + r) * DIM + scol;
    alds[rnd] = As + (wid * 16 + rnd * 64) * BK;
    blds[rnd] = Bs + (wid * 16 + rnd * 64) * BK;
  }

  f32x4 acc[4][4] = {};
  const int wr = wid >> 1, wc = wid & 1;
  const int fr = lane & 15, kb = (lane >> 4) * 8;

  for (int ks = 0; ks < DIM; ks += BK) {
    __syncthreads();
#pragma unroll
    for (int rnd = 0; rnd < 2; rnd++) {
      gl2lds16(arow[rnd] + ks, alds[rnd]);
      gl2lds16(brow[rnd] + ks, blds[rnd]);
    }
    __syncthreads();
    f16x8 af[4], bf[4];
#pragma unroll
    for (int m = 0; m < 4; m++)
      af[m] = *(const f16x8*)(As + (wr * 64 + m * 16 + fr) * BK + kb);
#pragma unroll
    for (int n = 0; n < 4; n++)
      bf[n] = *(const f16x8*)(Bs + (wc * 64 + n * 16 + fr) * BK + kb);
#pragma unroll
    for (int m = 0; m < 4; m++)
#pragma unroll
      for (int n = 0; n < 4; n++)
        acc[m][n] = __builtin_amdgcn_mfma_f32_16x16x32_f16(af[m], bf[n], acc[m][n], 0, 0, 0);
  }

  float bcol[4];
#pragma unroll
  for (int n = 0; n < 4; n++) bcol[n] = bias[e * ((MODE == 0) ? HIDN : DIM) + n0 + wc * 64 + n * 16 + fr];

  if (MODE == 0) {
#pragma unroll
    for (int m = 0; m < 4; m++)
#pragma unroll
      for (int r4 = 0; r4 < 4; r4++) {
        int slot = slot0 + wr * 64 + m * 16 + (lane >> 4) * 4 + r4;
#pragma unroll
        for (int n = 0; n < 4; n++) {
          int col = n0 + wc * 64 + n * 16 + fr;
          float v = acc[m][n][r4] + bcol[n];
          Hout[(size_t)(klist * SLOTS + slot) * HIDN + col] = (f16)fmaxf(v, 0.f);
        }
      }
  } else {
    const int vend = ao[e] + counts[klist * 8 + e];
#pragma unroll
    for (int m = 0; m < 4; m++)
#pragma unroll
      for (int r4 = 0; r4 < 4; r4++) {
        int slot = slot0 + wr * 64 + m * 16 + (lane >> 4) * 4 + r4;
        if (slot < vend) {
          int tk = toks[klist * SLOTS + slot];
          float w = wsl[klist * SLOTS + slot];
#pragma unroll
          for (int n = 0; n < 4; n++) {
            int col = n0 + wc * 64 + n * 16 + fr;
            float v = (acc[m][n][r4] + bcol[n]) * w;
            size_t oi = (size_t)tk * DIM + col;
            if (MODE == 1) y[oi] = v;
            else y[oi] += v;
          }
        }
      }
  }
}

// ---------- importance loss ----------
__global__ void k_imploss(const float* __restrict__ gp, float* __restrict__ loss) {
  __shared__ double simp[256][8];
  __shared__ double colsum[8];
  double im[8] = {0, 0, 0, 0, 0, 0, 0, 0};
  for (int n = threadIdx.x; n < NTOK; n += 256) {
#pragma unroll
    for (int e = 0; e < 8; e++) im[e] += (double)gp[(size_t)n * 8 + e];
  }
#pragma unroll
  for (int e = 0; e < 8; e++) simp[threadIdx.x][e] = im[e];
  __syncthreads();
  if (threadIdx.x < 8) {
    double s = 0.0;
    for (int t = 0; t < 256; t++) s += simp[t][threadIdx.x];
    colsum[threadIdx.x] = s;
  }
  __syncthreads();
  if (threadIdx.x == 0) {
    double m = 0.0;
    for (int e = 0; e < 8; e++) m += colsum[e];
    m *= (1.0 / 8.0);
    double var = 0.0;
    for (int e = 0; e < 8; e++) { double d = colsum[e] - m; var += d * d; }
    var *= (1.0 / 7.0);
    double r = sqrt(var) / m;
    loss[0] = (float)(0.01 * r * r);
  }
}

extern "C" void kernel_launch(void* const* d_in, const int* in_sizes, int n_in,
                              void* d_out, int out_size, void* d_ws, size_t ws_size,
                              hipStream_t stream) {
  const float* x  = (const float*)d_in[0];
  const float* q  = (const float*)d_in[1];
  const float* Wv = (const float*)d_in[6];
  const float* bv = (const float*)d_in[7];
  const float* Wo = (const float*)d_in[8];
  const float* bo = (const float*)d_in[9];
  const float* gW = (const float*)d_in[10];
  const float* gb = (const float*)d_in[11];
  const float* W1 = (const float*)d_in[12];
  const float* b1 = (const float*)d_in[13];
  const float* W2 = (const float*)d_in[14];
  const float* b2 = (const float*)d_in[15];

  float* out = (float*)d_out;
  float* y_out = out;
  float* gp_out = out + (size_t)NTOK * DIM;
  float* loss_out = gp_out + (size_t)NTOK * NEXP;

  uint8_t* w = (uint8_t*)d_ws;
  size_t o = 0;
  auto alloc = [&](size_t bytes) -> void* {
    void* p = w + o;
    o = (o + bytes + 255) & ~(size_t)255;
    return p;
  };
  f16* xh      = (f16*)alloc((size_t)NTOK * DIM * 2);
  f16* W1t     = (f16*)alloc((size_t)NEXP * DIM * HIDN * 2);
  f16* W2t     = (f16*)alloc((size_t)NEXP * DIM * HIDN * 2);
  f16* Hbuf    = (f16*)alloc((size_t)2 * SLOTS * HIDN * 2);
  double* G1   = (double*)alloc((size_t)DIM * NEXP * 8);
  double* Wg   = (double*)alloc((size_t)DIM * NEXP * 8);
  double* bg   = (double*)alloc(NEXP * 8);
  int* e1a     = (int*)alloc(NTOK * 4);
  int* e2a     = (int*)alloc(NTOK * 4);
  float* w1a   = (float*)alloc(NTOK * 4);
  float* w2a   = (float*)alloc(NTOK * 4);
  int* counts  = (int*)alloc(16 * 4);
  int* aoff    = (int*)alloc(18 * 4);
  int* cursors = (int*)alloc(16 * 4);
  int* toks    = (int*)alloc((size_t)2 * SLOTS * 4);
  float* wsl   = (float*)alloc((size_t)2 * SLOTS * 4);
  (void)ws_size; (void)in_sizes; (void)n_in; (void)out_size;

  k_conv_x<<<(NTOK * DIM / 4 + 255) / 256, 256, 0, stream>>>(x, xh);
  k_transpose_cast<<<dim3(16, 16, 8), 256, 0, stream>>>(W1, W1t);
  k_transpose_cast<<<dim3(16, 16, 8), 256, 0, stream>>>(W2, W2t);
  k_foldA<<<1024, 256, 0, stream>>>(Wo, gW, G1);
  k_foldB<<<1024, 256, 0, stream>>>(Wv, G1, Wg);
  k_foldbg<<<1, 256, 0, stream>>>(G1, bv, bo, gW, gb, bg);
  hipMemsetAsync(counts, 0, 16 * 4, stream);
  k_gate<<<NTOK / 4, 256, 0, stream>>>(q, Wg, bg, gp_out, e1a, e2a, w1a, w2a, counts);
  k_scan<<<1, 64, 0, stream>>>(counts, aoff, cursors);
  hipMemsetAsync(toks, 0, (size_t)2 * SLOTS * 4, stream);
  hipMemsetAsync(wsl, 0, (size_t)2 * SLOTS * 4, stream);
  k_scatter<<<NTOK / 256, 256, 0, stream>>>(e1a, e2a, w1a, w2a, aoff, cursors, toks, wsl);
  k_expert<0><<<dim3(MAXRB, 4, 2), 256, 0, stream>>>(xh, W1t, b1, toks, wsl, aoff, counts,
                                                     Hbuf, nullptr, 0);
  k_expert<1><<<dim3(MAXRB, 4, 1), 256, 0, stream>>>(Hbuf, W2t, b2, toks, wsl, aoff, counts,
                                                     nullptr, y_out, 0);
  k_expert<2><<<dim3(MAXRB, 4, 1), 256, 0, stream>>>(Hbuf, W2t, b2, toks, wsl, aoff, counts,
                                                     nullptr, y_out, 1);
  k_imploss<<<1, 256, 0, stream>>>(gp_out, loss_out);
}

// Round 2
// 198.896 us; speedup vs baseline: 1.9184x; 1.9184x over previous
//
#include <hip/hip_runtime.h>
#include <math.h>
#include <stdint.h>

#define NTOK 8192
#define DIM  512
#define NEXP 8
#define HIDN 512
#define BM 128
#define BN 128
#define BK 32
#define MAXRB 72              // ceil((8192 + 8*127)/128)
#define SLOTS (MAXRB*BM)      // 9216

typedef _Float16 f16;
typedef __attribute__((ext_vector_type(4))) _Float16 f16x4;
typedef __attribute__((ext_vector_type(8))) _Float16 f16x8;
typedef __attribute__((ext_vector_type(4))) float    f32x4;

__device__ __forceinline__ void gl2lds16(const void* g, void* l) {
  __builtin_amdgcn_global_load_lds(
      (const __attribute__((address_space(1))) unsigned int*)(g),
      (__attribute__((address_space(3))) unsigned int*)(l), 16, 0, 0);
}

// ---------- converts ----------
__global__ void k_conv_x(const float* __restrict__ x, f16* __restrict__ xh) {
  int i4 = (blockIdx.x * 256 + threadIdx.x) * 4;
  float4 v = *(const float4*)(x + i4);
  f16x4 o; o.x = (_Float16)v.x; o.y = (_Float16)v.y; o.z = (_Float16)v.z; o.w = (_Float16)v.w;
  *(f16x4*)(xh + i4) = o;
}

// W [E][K][N] fp32 -> Wt [E][N][K] f16
__global__ void k_transpose_cast(const float* __restrict__ W, f16* __restrict__ Wt) {
  __shared__ float t[32][33];
  int e = blockIdx.z;
  int k0 = blockIdx.x * 32, n0 = blockIdx.y * 32;
  const float* src = W + (size_t)e * DIM * DIM;
  f16* dst = Wt + (size_t)e * DIM * DIM;
  int tx = threadIdx.x & 31, ty = threadIdx.x >> 5;
  for (int r = ty; r < 32; r += 8) t[r][tx] = src[(size_t)(k0 + r) * DIM + n0 + tx];
  __syncthreads();
  for (int r = ty; r < 32; r += 8) dst[(size_t)(n0 + r) * DIM + k0 + tx] = (f16)t[tx][r];
}

// ---------- fp64 gate fold: Wg = Wv @ (Wo @ gate_W), bg folded ----------
__global__ void k_foldA(const float* __restrict__ Wo, const float* __restrict__ gW,
                        double* __restrict__ G1) {
  int out = blockIdx.x * 4 + (threadIdx.x >> 6);
  int lane = threadIdx.x & 63;
  int d = out >> 3, e = out & 7;
  double acc = 0.0;
#pragma unroll
  for (int j = 0; j < 8; j++) {
    int k = j * 64 + lane;
    acc += (double)Wo[d * DIM + k] * (double)gW[k * NEXP + e];
  }
#pragma unroll
  for (int off = 32; off; off >>= 1) acc += __shfl_xor(acc, off, 64);
  if (lane == 0) G1[out] = acc;
}

__global__ void k_foldB(const float* __restrict__ Wv, const double* __restrict__ G1,
                        float* __restrict__ Wg) {
  int out = blockIdx.x * 4 + (threadIdx.x >> 6);
  int lane = threadIdx.x & 63;
  int d = out >> 3, e = out & 7;
  double acc = 0.0;
#pragma unroll
  for (int j = 0; j < 8; j++) {
    int k = j * 64 + lane;
    acc += (double)Wv[d * DIM + k] * G1[k * NEXP + e];
  }
#pragma unroll
  for (int off = 32; off; off >>= 1) acc += __shfl_xor(acc, off, 64);
  if (lane == 0) Wg[out] = (float)acc;
}

__global__ void k_foldbg(const double* __restrict__ G1, const float* __restrict__ bv,
                         const float* __restrict__ bo, const float* __restrict__ gW,
                         const float* __restrict__ gb, double* __restrict__ bg) {
  int lane = threadIdx.x & 63, w = threadIdx.x >> 6;
  for (int e = w; e < NEXP; e += 4) {
    double acc = 0.0;
#pragma unroll
    for (int j = 0; j < 8; j++) {
      int d = j * 64 + lane;
      acc += (double)bv[d] * G1[d * NEXP + e] + (double)bo[d] * (double)gW[d * NEXP + e];
    }
#pragma unroll
    for (int off = 32; off; off >>= 1) acc += __shfl_xor(acc, off, 64);
    if (lane == 0) bg[e] = acc + (double)gb[e];
  }
}

// ---------- gate: thread-per-(token,expert,half); lane-parallel softmax/top2 ----------
// tid layout: e = tid&7, half = (tid>>3)&1, tl = tid>>4 (16 tokens/block)
__global__ __launch_bounds__(256) void k_gate(
    const float* __restrict__ q, const float* __restrict__ Wg,
    const double* __restrict__ bg, float* __restrict__ gp_out,
    int* __restrict__ e1a, int* __restrict__ e2a,
    float* __restrict__ w1a, float* __restrict__ w2a, int* __restrict__ counts) {
  __shared__ float qs[16 * 513];
  __shared__ int cnt[16];
  const int tid = threadIdx.x;
  const int tok0 = blockIdx.x * 16;

  for (int i = tid; i < 16 * 512; i += 256) {
    int r = i >> 9, c = i & 511;
    qs[r * 513 + c] = q[(size_t)(tok0 + r) * DIM + c];
  }
  if (tid < 16) cnt[tid] = 0;
  __syncthreads();

  const int e = tid & 7;
  const int half = (tid >> 3) & 1;
  const int tl = tid >> 4;
  const float* qrow = qs + tl * 513 + half * 256;
  const float* wcol = Wg + half * 256 * NEXP + e;

  double acc = 0.0;
#pragma unroll 8
  for (int j = 0; j < 256; j++)
    acc += (double)qrow[j] * (double)wcol[(size_t)j * NEXP];
  acc += __shfl_xor(acc, 8, 64);  // combine halves

  double l = acc + bg[e];
  double m = l;
#pragma unroll
  for (int off = 1; off < 8; off <<= 1) m = fmax(m, __shfl_xor(m, off, 64));
  double ex = exp(l - m);
  double s = ex;
#pragma unroll
  for (int off = 1; off < 8; off <<= 1) s += __shfl_xor(s, off, 64);
  double p = ex / s;
  int tok = tok0 + tl;
  if (half == 0) gp_out[(size_t)tok * NEXP + e] = (float)p;

  // top-1 with lowest-index tie-break
  double v1 = p; int i1 = e;
#pragma unroll
  for (int off = 1; off < 8; off <<= 1) {
    double ov = __shfl_xor(v1, off, 64);
    int oi = __shfl_xor(i1, off, 64);
    if (ov > v1 || (ov == v1 && oi < i1)) { v1 = ov; i1 = oi; }
  }
  // top-2
  double v2 = (e == i1) ? -1e300 : p; int i2 = e;
#pragma unroll
  for (int off = 1; off < 8; off <<= 1) {
    double ov = __shfl_xor(v2, off, 64);
    int oi = __shfl_xor(i2, off, 64);
    if (ov > v2 || (ov == v2 && oi < i2)) { v2 = ov; i2 = oi; }
  }
  if (e == 0 && half == 0) {
    double ev = exp(v2 - v1);
    double iw = 1.0 / (1.0 + ev);
    e1a[tok] = i1; e2a[tok] = i2;
    w1a[tok] = (float)iw; w2a[tok] = (float)(ev * iw);
    atomicAdd(&cnt[i1], 1);
    atomicAdd(&cnt[8 + i2], 1);
  }
  __syncthreads();
  if (tid < 16 && cnt[tid] > 0) atomicAdd(&counts[tid], cnt[tid]);
}

__global__ void k_scan(const int* __restrict__ counts, int* __restrict__ aoff,
                       int* __restrict__ cursors) {
  if (threadIdx.x == 0) {
    for (int k = 0; k < 2; k++) {
      int off = 0;
      for (int e = 0; e < NEXP; e++) {
        aoff[k * 9 + e] = off;
        off += (counts[k * 8 + e] + BM - 1) / BM * BM;
      }
      aoff[k * 9 + 8] = off;
    }
    for (int i = 0; i < 16; i++) cursors[i] = 0;
  }
}

__global__ void k_scatter(const int* __restrict__ e1a, const int* __restrict__ e2a,
                          const float* __restrict__ w1a, const float* __restrict__ w2a,
                          const int* __restrict__ aoff, int* __restrict__ cursors,
                          int* __restrict__ toks, float* __restrict__ wsl) {
  int n = blockIdx.x * 256 + threadIdx.x;
  int e1 = e1a[n];
  int pos = atomicAdd(&cursors[e1], 1);
  int slot = aoff[e1] + pos;
  toks[slot] = n; wsl[slot] = w1a[n];
  int e2 = e2a[n];
  pos = atomicAdd(&cursors[8 + e2], 1);
  slot = SLOTS + aoff[9 + e2] + pos;
  toks[slot] = n; wsl[slot] = w2a[n];
}

// ---------- expert GEMM: MODE 0 = layer1 (x->H, relu), 1 = layer2 k=0 (y=),
// 2 = layer2 k=1 (y+=) ----------
template <int MODE>
__global__ __launch_bounds__(256) void k_expert(
    const f16* __restrict__ Asrc, const f16* __restrict__ Wt,
    const float* __restrict__ bias, const int* __restrict__ toks,
    const float* __restrict__ wsl, const int* __restrict__ aoff,
    const int* __restrict__ counts, f16* __restrict__ Hout,
    float* __restrict__ y, int kpass) {
  const int klist = (MODE == 0) ? blockIdx.z : kpass;
  const int* ao = aoff + klist * 9;
  const int slot0 = blockIdx.x * BM;
  if (slot0 >= ao[8]) return;
  int e = 0;
#pragma unroll
  for (int t = 1; t <= 7; t++) if (slot0 >= ao[t]) e = t;

  const int n0 = blockIdx.y * BN;
  const int tid = threadIdx.x, lane = tid & 63, wid = tid >> 6;

  __shared__ __align__(16) f16 As[BM * BK];
  __shared__ __align__(16) f16 Bs[BN * BK];

  const int srow = wid * 16 + (lane >> 2);
  const int scol = (lane & 3) * 8;
  const f16* arow[2];
  const f16* brow[2];
  f16* alds[2];
  f16* blds[2];
#pragma unroll
  for (int rnd = 0; rnd < 2; rnd++) {
    int r = srow + rnd * 64;
    if (MODE == 0) {
      int tk = toks[klist * SLOTS + slot0 + r];
      arow[rnd] = Asrc + (size_t)tk * DIM + scol;
    } else {
      arow[rnd] = Asrc + (size_t)(klist * SLOTS + slot0 + r) * HIDN + scol;
    }
    brow[rnd] = Wt + ((size_t)e * DIM + n0 + r) * DIM + scol;
    alds[rnd] = As + (wid * 16 + rnd * 64) * BK;
    blds[rnd] = Bs + (wid * 16 + rnd * 64) * BK;
  }

  f32x4 acc[4][4] = {};
  const int wr = wid >> 1, wc = wid & 1;
  const int fr = lane & 15, kb = (lane >> 4) * 8;

  for (int ks = 0; ks < DIM; ks += BK) {
    __syncthreads();
#pragma unroll
    for (int rnd = 0; rnd < 2; rnd++) {
      gl2lds16(arow[rnd] + ks, alds[rnd]);
      gl2lds16(brow[rnd] + ks, blds[rnd]);
    }
    __syncthreads();
    f16x8 af[4], bf[4];
#pragma unroll
    for (int m = 0; m < 4; m++)
      af[m] = *(const f16x8*)(As + (wr * 64 + m * 16 + fr) * BK + kb);
#pragma unroll
    for (int n = 0; n < 4; n++)
      bf[n] = *(const f16x8*)(Bs + (wc * 64 + n * 16 + fr) * BK + kb);
#pragma unroll
    for (int m = 0; m < 4; m++)
#pragma unroll
      for (int n = 0; n < 4; n++)
        acc[m][n] = __builtin_amdgcn_mfma_f32_16x16x32_f16(af[m], bf[n], acc[m][n], 0, 0, 0);
  }

  float bcol[4];
#pragma unroll
  for (int n = 0; n < 4; n++) bcol[n] = bias[e * ((MODE == 0) ? HIDN : DIM) + n0 + wc * 64 + n * 16 + fr];

  if (MODE == 0) {
#pragma unroll
    for (int m = 0; m < 4; m++)
#pragma unroll
      for (int r4 = 0; r4 < 4; r4++) {
        int slot = slot0 + wr * 64 + m * 16 + (lane >> 4) * 4 + r4;
#pragma unroll
        for (int n = 0; n < 4; n++) {
          int col = n0 + wc * 64 + n * 16 + fr;
          float v = acc[m][n][r4] + bcol[n];
          Hout[(size_t)(klist * SLOTS + slot) * HIDN + col] = (f16)fmaxf(v, 0.f);
        }
      }
  } else {
    const int vend = ao[e] + counts[klist * 8 + e];
#pragma unroll
    for (int m = 0; m < 4; m++)
#pragma unroll
      for (int r4 = 0; r4 < 4; r4++) {
        int slot = slot0 + wr * 64 + m * 16 + (lane >> 4) * 4 + r4;
        if (slot < vend) {
          int tk = toks[klist * SLOTS + slot];
          float w = wsl[klist * SLOTS + slot];
#pragma unroll
          for (int n = 0; n < 4; n++) {
            int col = n0 + wc * 64 + n * 16 + fr;
            float v = (acc[m][n][r4] + bcol[n]) * w;
            size_t oi = (size_t)tk * DIM + col;
            if (MODE == 1) y[oi] = v;
            else y[oi] += v;
          }
        }
      }
  }
}

// ---------- importance loss ----------
__global__ void k_imploss(const float* __restrict__ gp, float* __restrict__ loss) {
  __shared__ double simp[256][8];
  __shared__ double colsum[8];
  double im[8] = {0, 0, 0, 0, 0, 0, 0, 0};
  for (int n = threadIdx.x; n < NTOK; n += 256) {
#pragma unroll
    for (int e = 0; e < 8; e++) im[e] += (double)gp[(size_t)n * 8 + e];
  }
#pragma unroll
  for (int e = 0; e < 8; e++) simp[threadIdx.x][e] = im[e];
  __syncthreads();
  if (threadIdx.x < 8) {
    double s = 0.0;
    for (int t = 0; t < 256; t++) s += simp[t][threadIdx.x];
    colsum[threadIdx.x] = s;
  }
  __syncthreads();
  if (threadIdx.x == 0) {
    double m = 0.0;
    for (int e = 0; e < 8; e++) m += colsum[e];
    m *= (1.0 / 8.0);
    double var = 0.0;
    for (int e = 0; e < 8; e++) { double d = colsum[e] - m; var += d * d; }
    var *= (1.0 / 7.0);
    double r = sqrt(var) / m;
    loss[0] = (float)(0.01 * r * r);
  }
}

extern "C" void kernel_launch(void* const* d_in, const int* in_sizes, int n_in,
                              void* d_out, int out_size, void* d_ws, size_t ws_size,
                              hipStream_t stream) {
  const float* x  = (const float*)d_in[0];
  const float* q  = (const float*)d_in[1];
  const float* Wv = (const float*)d_in[6];
  const float* bv = (const float*)d_in[7];
  const float* Wo = (const float*)d_in[8];
  const float* bo = (const float*)d_in[9];
  const float* gW = (const float*)d_in[10];
  const float* gb = (const float*)d_in[11];
  const float* W1 = (const float*)d_in[12];
  const float* b1 = (const float*)d_in[13];
  const float* W2 = (const float*)d_in[14];
  const float* b2 = (const float*)d_in[15];

  float* out = (float*)d_out;
  float* y_out = out;
  float* gp_out = out + (size_t)NTOK * DIM;
  float* loss_out = gp_out + (size_t)NTOK * NEXP;

  uint8_t* w = (uint8_t*)d_ws;
  size_t o = 0;
  auto alloc = [&](size_t bytes) -> void* {
    void* p = w + o;
    o = (o + bytes + 255) & ~(size_t)255;
    return p;
  };
  f16* xh      = (f16*)alloc((size_t)NTOK * DIM * 2);
  f16* W1t     = (f16*)alloc((size_t)NEXP * DIM * HIDN * 2);
  f16* W2t     = (f16*)alloc((size_t)NEXP * DIM * HIDN * 2);
  f16* Hbuf    = (f16*)alloc((size_t)2 * SLOTS * HIDN * 2);
  double* G1   = (double*)alloc((size_t)DIM * NEXP * 8);
  float* Wg    = (float*)alloc((size_t)DIM * NEXP * 4);
  double* bg   = (double*)alloc(NEXP * 8);
  int* e1a     = (int*)alloc(NTOK * 4);
  int* e2a     = (int*)alloc(NTOK * 4);
  float* w1a   = (float*)alloc(NTOK * 4);
  float* w2a   = (float*)alloc(NTOK * 4);
  int* counts  = (int*)alloc(16 * 4);
  int* aoff    = (int*)alloc(18 * 4);
  int* cursors = (int*)alloc(16 * 4);
  int* toks    = (int*)alloc((size_t)2 * SLOTS * 4);
  float* wsl   = (float*)alloc((size_t)2 * SLOTS * 4);
  (void)ws_size; (void)in_sizes; (void)n_in; (void)out_size;

  k_conv_x<<<(NTOK * DIM / 4 + 255) / 256, 256, 0, stream>>>(x, xh);
  k_transpose_cast<<<dim3(16, 16, 8), 256, 0, stream>>>(W1, W1t);
  k_transpose_cast<<<dim3(16, 16, 8), 256, 0, stream>>>(W2, W2t);
  k_foldA<<<1024, 256, 0, stream>>>(Wo, gW, G1);
  k_foldB<<<1024, 256, 0, stream>>>(Wv, G1, Wg);
  k_foldbg<<<1, 256, 0, stream>>>(G1, bv, bo, gW, gb, bg);
  hipMemsetAsync(counts, 0, 16 * 4, stream);
  k_gate<<<NTOK / 16, 256, 0, stream>>>(q, Wg, bg, gp_out, e1a, e2a, w1a, w2a, counts);
  k_scan<<<1, 64, 0, stream>>>(counts, aoff, cursors);
  hipMemsetAsync(toks, 0, (size_t)2 * SLOTS * 4, stream);
  hipMemsetAsync(wsl, 0, (size_t)2 * SLOTS * 4, stream);
  k_scatter<<<NTOK / 256, 256, 0, stream>>>(e1a, e2a, w1a, w2a, aoff, cursors, toks, wsl);
  k_expert<0><<<dim3(MAXRB, 4, 2), 256, 0, stream>>>(xh, W1t, b1, toks, wsl, aoff, counts,
                                                     Hbuf, nullptr, 0);
  k_expert<1><<<dim3(MAXRB, 4, 1), 256, 0, stream>>>(Hbuf, W2t, b2, toks, wsl, aoff, counts,
                                                     nullptr, y_out, 0);
  k_expert<2><<<dim3(MAXRB, 4, 1), 256, 0, stream>>>(Hbuf, W2t, b2, toks, wsl, aoff, counts,
                                                     nullptr, y_out, 1);
  k_imploss<<<1, 256, 0, stream>>>(gp_out, loss_out);
}

// Round 3
// 135.211 us; speedup vs baseline: 2.8220x; 1.4710x over previous
//
#include <hip/hip_runtime.h>
#include <math.h>
#include <stdint.h>

#define NTOK 8192
#define DIM  512
#define NEXP 8
#define HIDN 512
#define BM 128
#define BN 128
#define BK 32
#define MAXRB 72              // ceil((8192 + 8*127)/128)
#define SLOTS (MAXRB*BM)      // 9216
#define GBLK (NTOK/16)        // 512 gate blocks (16 tokens each)

typedef _Float16 f16;
typedef __attribute__((ext_vector_type(4))) _Float16 f16x4;
typedef __attribute__((ext_vector_type(8))) _Float16 f16x8;
typedef __attribute__((ext_vector_type(4))) float    f32x4;

__device__ __forceinline__ void gl2lds16(const void* g, void* l) {
  __builtin_amdgcn_global_load_lds(
      (const __attribute__((address_space(1))) unsigned int*)(g),
      (__attribute__((address_space(3))) unsigned int*)(l), 16, 0, 0);
}

// ---------- converts ----------
__global__ void k_conv_x(const float* __restrict__ x, f16* __restrict__ xh) {
  int i4 = (blockIdx.x * 256 + threadIdx.x) * 4;
  float4 v = *(const float4*)(x + i4);
  f16x4 o; o.x = (_Float16)v.x; o.y = (_Float16)v.y; o.z = (_Float16)v.z; o.w = (_Float16)v.w;
  *(f16x4*)(xh + i4) = o;
}

// W [E][K][N] fp32 -> Wt [E][N][K] f16
__global__ void k_transpose_cast(const float* __restrict__ W, f16* __restrict__ Wt) {
  __shared__ float t[32][33];
  int e = blockIdx.z;
  int k0 = blockIdx.x * 32, n0 = blockIdx.y * 32;
  const float* src = W + (size_t)e * DIM * DIM;
  f16* dst = Wt + (size_t)e * DIM * DIM;
  int tx = threadIdx.x & 31, ty = threadIdx.x >> 5;
  for (int r = ty; r < 32; r += 8) t[r][tx] = src[(size_t)(k0 + r) * DIM + n0 + tx];
  __syncthreads();
  for (int r = ty; r < 32; r += 8) dst[(size_t)(n0 + r) * DIM + k0 + tx] = (f16)t[tx][r];
}

// ---------- fp64 gate fold: Wg = Wv @ (Wo @ gate_W), bg folded ----------
__global__ void k_foldA(const float* __restrict__ Wo, const float* __restrict__ gW,
                        double* __restrict__ G1) {
  int out = blockIdx.x * 4 + (threadIdx.x >> 6);
  int lane = threadIdx.x & 63;
  int d = out >> 3, e = out & 7;
  double acc = 0.0;
#pragma unroll
  for (int j = 0; j < 8; j++) {
    int k = j * 64 + lane;
    acc += (double)Wo[d * DIM + k] * (double)gW[k * NEXP + e];
  }
#pragma unroll
  for (int off = 32; off; off >>= 1) acc += __shfl_xor(acc, off, 64);
  if (lane == 0) G1[out] = acc;
}

// blocks 0..1023: Wg = fp32(Wv @ G1). block 1024: bg fold.
__global__ void k_foldB(const float* __restrict__ Wv, const double* __restrict__ G1,
                        float* __restrict__ Wg, const float* __restrict__ bv,
                        const float* __restrict__ bo, const float* __restrict__ gW,
                        const float* __restrict__ gb, double* __restrict__ bg) {
  int lane = threadIdx.x & 63;
  if (blockIdx.x == 1024) {
    int w = threadIdx.x >> 6;
    for (int e = w; e < NEXP; e += 4) {
      double acc = 0.0;
#pragma unroll
      for (int j = 0; j < 8; j++) {
        int d = j * 64 + lane;
        acc += (double)bv[d] * G1[d * NEXP + e] + (double)bo[d] * (double)gW[d * NEXP + e];
      }
#pragma unroll
      for (int off = 32; off; off >>= 1) acc += __shfl_xor(acc, off, 64);
      if (lane == 0) bg[e] = acc + (double)gb[e];
    }
    return;
  }
  int out = blockIdx.x * 4 + (threadIdx.x >> 6);
  int d = out >> 3, e = out & 7;
  double acc = 0.0;
#pragma unroll
  for (int j = 0; j < 8; j++) {
    int k = j * 64 + lane;
    acc += (double)Wv[d * DIM + k] * G1[k * NEXP + e];
  }
#pragma unroll
  for (int off = 32; off; off >>= 1) acc += __shfl_xor(acc, off, 64);
  if (lane == 0) Wg[out] = (float)acc;
}

// ---------- gate: thread-per-(token,expert,half); lane-parallel softmax/top2 ----------
// tid layout: e = tid&7, half = (tid>>3)&1, tl = tid>>4 (16 tokens/block)
// Outputs per-block histogram + per-token local rank (no global atomics).
__global__ __launch_bounds__(256) void k_gate(
    const float* __restrict__ q, const float* __restrict__ Wg,
    const double* __restrict__ bg, float* __restrict__ gp_out,
    int* __restrict__ e1a, int* __restrict__ e2a,
    float* __restrict__ w1a, float* __restrict__ w2a,
    int* __restrict__ r1a, int* __restrict__ r2a, int* __restrict__ hist) {
  __shared__ float qs[16 * 513];
  __shared__ int cnt[16];
  const int tid = threadIdx.x;
  const int tok0 = blockIdx.x * 16;

  for (int i = tid; i < 16 * 512; i += 256) {
    int r = i >> 9, c = i & 511;
    qs[r * 513 + c] = q[(size_t)(tok0 + r) * DIM + c];
  }
  if (tid < 16) cnt[tid] = 0;
  __syncthreads();

  const int e = tid & 7;
  const int half = (tid >> 3) & 1;
  const int tl = tid >> 4;
  const float* qrow = qs + tl * 513 + half * 256;
  const float* wcol = Wg + half * 256 * NEXP + e;

  double acc = 0.0;
#pragma unroll 8
  for (int j = 0; j < 256; j++)
    acc += (double)qrow[j] * (double)wcol[(size_t)j * NEXP];
  acc += __shfl_xor(acc, 8, 64);  // combine halves

  double l = acc + bg[e];
  double m = l;
#pragma unroll
  for (int off = 1; off < 8; off <<= 1) m = fmax(m, __shfl_xor(m, off, 64));
  double ex = exp(l - m);
  double s = ex;
#pragma unroll
  for (int off = 1; off < 8; off <<= 1) s += __shfl_xor(s, off, 64);
  double p = ex / s;
  int tok = tok0 + tl;
  if (half == 0) gp_out[(size_t)tok * NEXP + e] = (float)p;

  // top-1 with lowest-index tie-break
  double v1 = p; int i1 = e;
#pragma unroll
  for (int off = 1; off < 8; off <<= 1) {
    double ov = __shfl_xor(v1, off, 64);
    int oi = __shfl_xor(i1, off, 64);
    if (ov > v1 || (ov == v1 && oi < i1)) { v1 = ov; i1 = oi; }
  }
  // top-2
  double v2 = (e == i1) ? -1e300 : p; int i2 = e;
#pragma unroll
  for (int off = 1; off < 8; off <<= 1) {
    double ov = __shfl_xor(v2, off, 64);
    int oi = __shfl_xor(i2, off, 64);
    if (ov > v2 || (ov == v2 && oi < i2)) { v2 = ov; i2 = oi; }
  }
  if (e == 0 && half == 0) {
    double ev = exp(v2 - v1);
    double iw = 1.0 / (1.0 + ev);
    e1a[tok] = i1; e2a[tok] = i2;
    w1a[tok] = (float)iw; w2a[tok] = (float)(ev * iw);
    r1a[tok] = atomicAdd(&cnt[i1], 1);
    r2a[tok] = atomicAdd(&cnt[8 + i2], 1);
  }
  __syncthreads();
  if (tid < 16) hist[blockIdx.x * 16 + tid] = cnt[tid];
}

// ---------- scan: per-counter exclusive prefix over gate blocks ----------
__global__ __launch_bounds__(1024) void k_scan2(const int* __restrict__ hist,
                                                int* __restrict__ blockbase,
                                                int* __restrict__ aoff,
                                                int* __restrict__ counts) {
  __shared__ int tot[16];
  const int c = threadIdx.x >> 6;   // counter 0..15
  const int l = threadIdx.x & 63;
  int v[GBLK / 64];
  int s = 0;
#pragma unroll
  for (int j = 0; j < GBLK / 64; j++) {
    v[j] = hist[((l * (GBLK / 64) + j) << 4) + c];
    s += v[j];
  }
  int incl = s;
#pragma unroll
  for (int off = 1; off < 64; off <<= 1) {
    int t = __shfl_up(incl, off, 64);
    if (l >= off) incl += t;
  }
  int run = incl - s;  // exclusive
#pragma unroll
  for (int j = 0; j < GBLK / 64; j++) {
    blockbase[((l * (GBLK / 64) + j) << 4) + c] = run;
    run += v[j];
  }
  if (l == 63) tot[c] = incl;
  __syncthreads();
  if (threadIdx.x == 0) {
    int o0 = 0, o1 = 0;
    for (int e = 0; e < NEXP; e++) {
      counts[e] = tot[e];
      aoff[e] = o0; o0 += (tot[e] + BM - 1) / BM * BM;
      counts[8 + e] = tot[8 + e];
      aoff[9 + e] = o1; o1 += (tot[8 + e] + BM - 1) / BM * BM;
    }
    aoff[8] = o0; aoff[17] = o1;
  }
}

// ---------- scatter: slot = aoff + blockbase + rank (no atomics) ----------
__global__ void k_scatter2(const int* __restrict__ e1a, const int* __restrict__ e2a,
                           const float* __restrict__ w1a, const float* __restrict__ w2a,
                           const int* __restrict__ r1a, const int* __restrict__ r2a,
                           const int* __restrict__ blockbase, const int* __restrict__ aoff,
                           int* __restrict__ toks, float* __restrict__ wsl) {
  int n = blockIdx.x * 256 + threadIdx.x;
  int blk = n >> 4;
  int e1 = e1a[n];
  int slot = aoff[e1] + blockbase[(blk << 4) + e1] + r1a[n];
  toks[slot] = n; wsl[slot] = w1a[n];
  int e2 = e2a[n];
  slot = SLOTS + aoff[9 + e2] + blockbase[(blk << 4) + 8 + e2] + r2a[n];
  toks[slot] = n; wsl[slot] = w2a[n];
}

// ---------- expert GEMM: MODE 0 = layer1 (x->H, relu), 1 = layer2 k=0 (y=),
// 2 = layer2 k=1 (y+=) ----------
template <int MODE>
__global__ __launch_bounds__(256) void k_expert(
    const f16* __restrict__ Asrc, const f16* __restrict__ Wt,
    const float* __restrict__ bias, const int* __restrict__ toks,
    const float* __restrict__ wsl, const int* __restrict__ aoff,
    const int* __restrict__ counts, f16* __restrict__ Hout,
    float* __restrict__ y, int kpass) {
  const int klist = (MODE == 0) ? blockIdx.z : kpass;
  const int* ao = aoff + klist * 9;
  const int slot0 = blockIdx.x * BM;
  if (slot0 >= ao[8]) return;
  int e = 0;
#pragma unroll
  for (int t = 1; t <= 7; t++) if (slot0 >= ao[t]) e = t;

  const int n0 = blockIdx.y * BN;
  const int tid = threadIdx.x, lane = tid & 63, wid = tid >> 6;

  __shared__ __align__(16) f16 As[BM * BK];
  __shared__ __align__(16) f16 Bs[BN * BK];

  const int srow = wid * 16 + (lane >> 2);
  const int scol = (lane & 3) * 8;
  const f16* arow[2];
  const f16* brow[2];
  f16* alds[2];
  f16* blds[2];
#pragma unroll
  for (int rnd = 0; rnd < 2; rnd++) {
    int r = srow + rnd * 64;
    if (MODE == 0) {
      int tk = toks[klist * SLOTS + slot0 + r];
      arow[rnd] = Asrc + (size_t)tk * DIM + scol;
    } else {
      arow[rnd] = Asrc + (size_t)(klist * SLOTS + slot0 + r) * HIDN + scol;
    }
    brow[rnd] = Wt + ((size_t)e * DIM + n0 + r) * DIM + scol;
    alds[rnd] = As + (wid * 16 + rnd * 64) * BK;
    blds[rnd] = Bs + (wid * 16 + rnd * 64) * BK;
  }

  f32x4 acc[4][4] = {};
  const int wr = wid >> 1, wc = wid & 1;
  const int fr = lane & 15, kb = (lane >> 4) * 8;

  for (int ks = 0; ks < DIM; ks += BK) {
    __syncthreads();
#pragma unroll
    for (int rnd = 0; rnd < 2; rnd++) {
      gl2lds16(arow[rnd] + ks, alds[rnd]);
      gl2lds16(brow[rnd] + ks, blds[rnd]);
    }
    __syncthreads();
    f16x8 af[4], bf[4];
#pragma unroll
    for (int m = 0; m < 4; m++)
      af[m] = *(const f16x8*)(As + (wr * 64 + m * 16 + fr) * BK + kb);
#pragma unroll
    for (int n = 0; n < 4; n++)
      bf[n] = *(const f16x8*)(Bs + (wc * 64 + n * 16 + fr) * BK + kb);
#pragma unroll
    for (int m = 0; m < 4; m++)
#pragma unroll
      for (int n = 0; n < 4; n++)
        acc[m][n] = __builtin_amdgcn_mfma_f32_16x16x32_f16(af[m], bf[n], acc[m][n], 0, 0, 0);
  }

  float bcol[4];
#pragma unroll
  for (int n = 0; n < 4; n++) bcol[n] = bias[e * ((MODE == 0) ? HIDN : DIM) + n0 + wc * 64 + n * 16 + fr];

  if (MODE == 0) {
#pragma unroll
    for (int m = 0; m < 4; m++)
#pragma unroll
      for (int r4 = 0; r4 < 4; r4++) {
        int slot = slot0 + wr * 64 + m * 16 + (lane >> 4) * 4 + r4;
#pragma unroll
        for (int n = 0; n < 4; n++) {
          int col = n0 + wc * 64 + n * 16 + fr;
          float v = acc[m][n][r4] + bcol[n];
          Hout[(size_t)(klist * SLOTS + slot) * HIDN + col] = (f16)fmaxf(v, 0.f);
        }
      }
  } else {
    const int vend = ao[e] + counts[klist * 8 + e];
#pragma unroll
    for (int m = 0; m < 4; m++)
#pragma unroll
      for (int r4 = 0; r4 < 4; r4++) {
        int slot = slot0 + wr * 64 + m * 16 + (lane >> 4) * 4 + r4;
        if (slot < vend) {
          int tk = toks[klist * SLOTS + slot];
          float w = wsl[klist * SLOTS + slot];
#pragma unroll
          for (int n = 0; n < 4; n++) {
            int col = n0 + wc * 64 + n * 16 + fr;
            float v = (acc[m][n][r4] + bcol[n]) * w;
            size_t oi = (size_t)tk * DIM + col;
            if (MODE == 1) y[oi] = v;
            else y[oi] += v;
          }
        }
      }
  }
}

// ---------- importance loss ----------
__global__ void k_imploss(const float* __restrict__ gp, float* __restrict__ loss) {
  __shared__ double simp[256][8];
  __shared__ double colsum[8];
  double im[8] = {0, 0, 0, 0, 0, 0, 0, 0};
  for (int n = threadIdx.x; n < NTOK; n += 256) {
#pragma unroll
    for (int e = 0; e < 8; e++) im[e] += (double)gp[(size_t)n * 8 + e];
  }
#pragma unroll
  for (int e = 0; e < 8; e++) simp[threadIdx.x][e] = im[e];
  __syncthreads();
  if (threadIdx.x < 8) {
    double s = 0.0;
    for (int t = 0; t < 256; t++) s += simp[t][threadIdx.x];
    colsum[threadIdx.x] = s;
  }
  __syncthreads();
  if (threadIdx.x == 0) {
    double m = 0.0;
    for (int e = 0; e < 8; e++) m += colsum[e];
    m *= (1.0 / 8.0);
    double var = 0.0;
    for (int e = 0; e < 8; e++) { double d = colsum[e] - m; var += d * d; }
    var *= (1.0 / 7.0);
    double r = sqrt(var) / m;
    loss[0] = (float)(0.01 * r * r);
  }
}

extern "C" void kernel_launch(void* const* d_in, const int* in_sizes, int n_in,
                              void* d_out, int out_size, void* d_ws, size_t ws_size,
                              hipStream_t stream) {
  const float* x  = (const float*)d_in[0];
  const float* q  = (const float*)d_in[1];
  const float* Wv = (const float*)d_in[6];
  const float* bv = (const float*)d_in[7];
  const float* Wo = (const float*)d_in[8];
  const float* bo = (const float*)d_in[9];
  const float* gW = (const float*)d_in[10];
  const float* gb = (const float*)d_in[11];
  const float* W1 = (const float*)d_in[12];
  const float* b1 = (const float*)d_in[13];
  const float* W2 = (const float*)d_in[14];
  const float* b2 = (const float*)d_in[15];

  float* out = (float*)d_out;
  float* y_out = out;
  float* gp_out = out + (size_t)NTOK * DIM;
  float* loss_out = gp_out + (size_t)NTOK * NEXP;

  uint8_t* w = (uint8_t*)d_ws;
  size_t o = 0;
  auto alloc = [&](size_t bytes) -> void* {
    void* p = w + o;
    o = (o + bytes + 255) & ~(size_t)255;
    return p;
  };
  f16* xh      = (f16*)alloc((size_t)NTOK * DIM * 2);
  f16* W1t     = (f16*)alloc((size_t)NEXP * DIM * HIDN * 2);
  f16* W2t     = (f16*)alloc((size_t)NEXP * DIM * HIDN * 2);
  f16* Hbuf    = (f16*)alloc((size_t)2 * SLOTS * HIDN * 2);
  double* G1   = (double*)alloc((size_t)DIM * NEXP * 8);
  float* Wg    = (float*)alloc((size_t)DIM * NEXP * 4);
  double* bg   = (double*)alloc(NEXP * 8);
  int* e1a     = (int*)alloc(NTOK * 4);
  int* e2a     = (int*)alloc(NTOK * 4);
  float* w1a   = (float*)alloc(NTOK * 4);
  float* w2a   = (float*)alloc(NTOK * 4);
  int* r1a     = (int*)alloc(NTOK * 4);
  int* r2a     = (int*)alloc(NTOK * 4);
  int* hist    = (int*)alloc((size_t)GBLK * 16 * 4);
  int* bbase   = (int*)alloc((size_t)GBLK * 16 * 4);
  int* counts  = (int*)alloc(16 * 4);
  int* aoff    = (int*)alloc(18 * 4);
  int* toks    = (int*)alloc((size_t)2 * SLOTS * 4);
  float* wsl   = (float*)alloc((size_t)2 * SLOTS * 4);
  (void)ws_size; (void)in_sizes; (void)n_in; (void)out_size;

  k_conv_x<<<(NTOK * DIM / 4 + 255) / 256, 256, 0, stream>>>(x, xh);
  k_transpose_cast<<<dim3(16, 16, 8), 256, 0, stream>>>(W1, W1t);
  k_transpose_cast<<<dim3(16, 16, 8), 256, 0, stream>>>(W2, W2t);
  k_foldA<<<1024, 256, 0, stream>>>(Wo, gW, G1);
  k_foldB<<<1025, 256, 0, stream>>>(Wv, G1, Wg, bv, bo, gW, gb, bg);
  k_gate<<<GBLK, 256, 0, stream>>>(q, Wg, bg, gp_out, e1a, e2a, w1a, w2a, r1a, r2a, hist);
  k_scan2<<<1, 1024, 0, stream>>>(hist, bbase, aoff, counts);
  hipMemsetAsync(toks, 0, (size_t)2 * SLOTS * 4, stream);
  k_scatter2<<<NTOK / 256, 256, 0, stream>>>(e1a, e2a, w1a, w2a, r1a, r2a, bbase, aoff, toks, wsl);
  k_expert<0><<<dim3(MAXRB, 4, 2), 256, 0, stream>>>(xh, W1t, b1, toks, wsl, aoff, counts,
                                                     Hbuf, nullptr, 0);
  k_expert<1><<<dim3(MAXRB, 4, 1), 256, 0, stream>>>(Hbuf, W2t, b2, toks, wsl, aoff, counts,
                                                     nullptr, y_out, 0);
  k_expert<2><<<dim3(MAXRB, 4, 1), 256, 0, stream>>>(Hbuf, W2t, b2, toks, wsl, aoff, counts,
                                                     nullptr, y_out, 1);
  k_imploss<<<1, 256, 0, stream>>>(gp_out, loss_out);
}

// Round 4
// 131.812 us; speedup vs baseline: 2.8947x; 1.0258x over previous
//
#include <hip/hip_runtime.h>
#include <math.h>
#include <stdint.h>

#define NTOK 8192
#define DIM  512
#define NEXP 8
#define HIDN 512
#define BM 128
#define BN 128
#define BK 32
#define MAXRB 72              // ceil((8192 + 8*127)/128)
#define SLOTS (MAXRB*BM)      // 9216
#define GBLK (NTOK/16)        // 512 gate blocks (16 tokens each)

typedef _Float16 f16;
typedef __attribute__((ext_vector_type(4))) _Float16 f16x4;
typedef __attribute__((ext_vector_type(8))) _Float16 f16x8;
typedef __attribute__((ext_vector_type(4))) float    f32x4;

__device__ __forceinline__ void gl2lds16(const void* g, void* l) {
  __builtin_amdgcn_global_load_lds(
      (const __attribute__((address_space(1))) unsigned int*)(g),
      (__attribute__((address_space(3))) unsigned int*)(l), 16, 0, 0);
}

// ---------- converts ----------
__global__ void k_conv_x(const float* __restrict__ x, f16* __restrict__ xh) {
  int i4 = (blockIdx.x * 256 + threadIdx.x) * 4;
  float4 v = *(const float4*)(x + i4);
  f16x4 o; o.x = (_Float16)v.x; o.y = (_Float16)v.y; o.z = (_Float16)v.z; o.w = (_Float16)v.w;
  *(f16x4*)(xh + i4) = o;
}

// W [E][K][N] fp32 -> Wt [E][N][K] f16 ; z<8: W1, z>=8: W2
__global__ void k_transpose_cast2(const float* __restrict__ W1, const float* __restrict__ W2,
                                  f16* __restrict__ W1t, f16* __restrict__ W2t) {
  __shared__ float t[32][33];
  int z = blockIdx.z;
  const float* src = (z < 8 ? W1 : W2) + (size_t)(z & 7) * DIM * DIM;
  f16* dst = (z < 8 ? W1t : W2t) + (size_t)(z & 7) * DIM * DIM;
  int k0 = blockIdx.x * 32, n0 = blockIdx.y * 32;
  int tx = threadIdx.x & 31, ty = threadIdx.x >> 5;
  for (int r = ty; r < 32; r += 8) t[r][tx] = src[(size_t)(k0 + r) * DIM + n0 + tx];
  __syncthreads();
  for (int r = ty; r < 32; r += 8) dst[(size_t)(n0 + r) * DIM + k0 + tx] = (f16)t[tx][r];
}

// ---------- fp64 gate fold: Wg = Wv @ (Wo @ gate_W), bg folded ----------
__global__ void k_foldA(const float* __restrict__ Wo, const float* __restrict__ gW,
                        double* __restrict__ G1) {
  int out = blockIdx.x * 4 + (threadIdx.x >> 6);
  int lane = threadIdx.x & 63;
  int d = out >> 3, e = out & 7;
  double acc = 0.0;
#pragma unroll
  for (int j = 0; j < 8; j++) {
    int k = j * 64 + lane;
    acc += (double)Wo[d * DIM + k] * (double)gW[k * NEXP + e];
  }
#pragma unroll
  for (int off = 32; off; off >>= 1) acc += __shfl_xor(acc, off, 64);
  if (lane == 0) G1[out] = acc;
}

// blocks 0..1023: Wg = fp32(Wv @ G1). block 1024: bg fold.
__global__ void k_foldB(const float* __restrict__ Wv, const double* __restrict__ G1,
                        float* __restrict__ Wg, const float* __restrict__ bv,
                        const float* __restrict__ bo, const float* __restrict__ gW,
                        const float* __restrict__ gb, double* __restrict__ bg) {
  int lane = threadIdx.x & 63;
  if (blockIdx.x == 1024) {
    int w = threadIdx.x >> 6;
    for (int e = w; e < NEXP; e += 4) {
      double acc = 0.0;
#pragma unroll
      for (int j = 0; j < 8; j++) {
        int d = j * 64 + lane;
        acc += (double)bv[d] * G1[d * NEXP + e] + (double)bo[d] * (double)gW[d * NEXP + e];
      }
#pragma unroll
      for (int off = 32; off; off >>= 1) acc += __shfl_xor(acc, off, 64);
      if (lane == 0) bg[e] = acc + (double)gb[e];
    }
    return;
  }
  int out = blockIdx.x * 4 + (threadIdx.x >> 6);
  int d = out >> 3, e = out & 7;
  double acc = 0.0;
#pragma unroll
  for (int j = 0; j < 8; j++) {
    int k = j * 64 + lane;
    acc += (double)Wv[d * DIM + k] * G1[k * NEXP + e];
  }
#pragma unroll
  for (int off = 32; off; off >>= 1) acc += __shfl_xor(acc, off, 64);
  if (lane == 0) Wg[out] = (float)acc;
}

// ---------- gate: thread-per-(token,expert,half); lane-parallel softmax/top2 ----------
__global__ __launch_bounds__(256) void k_gate(
    const float* __restrict__ q, const float* __restrict__ Wg,
    const double* __restrict__ bg, float* __restrict__ gp_out,
    int* __restrict__ e1a, int* __restrict__ e2a,
    float* __restrict__ w1a, float* __restrict__ w2a,
    int* __restrict__ r1a, int* __restrict__ r2a, int* __restrict__ hist) {
  __shared__ float qs[16 * 513];
  __shared__ int cnt[16];
  const int tid = threadIdx.x;
  const int tok0 = blockIdx.x * 16;

  for (int i = tid; i < 16 * 512; i += 256) {
    int r = i >> 9, c = i & 511;
    qs[r * 513 + c] = q[(size_t)(tok0 + r) * DIM + c];
  }
  if (tid < 16) cnt[tid] = 0;
  __syncthreads();

  const int e = tid & 7;
  const int half = (tid >> 3) & 1;
  const int tl = tid >> 4;
  const float* qrow = qs + tl * 513 + half * 256;
  const float* wcol = Wg + half * 256 * NEXP + e;

  double acc = 0.0;
#pragma unroll 8
  for (int j = 0; j < 256; j++)
    acc += (double)qrow[j] * (double)wcol[(size_t)j * NEXP];
  acc += __shfl_xor(acc, 8, 64);  // combine halves

  double l = acc + bg[e];
  double m = l;
#pragma unroll
  for (int off = 1; off < 8; off <<= 1) m = fmax(m, __shfl_xor(m, off, 64));
  double ex = exp(l - m);
  double s = ex;
#pragma unroll
  for (int off = 1; off < 8; off <<= 1) s += __shfl_xor(s, off, 64);
  double p = ex / s;
  int tok = tok0 + tl;
  if (half == 0) gp_out[(size_t)tok * NEXP + e] = (float)p;

  // top-1 with lowest-index tie-break
  double v1 = p; int i1 = e;
#pragma unroll
  for (int off = 1; off < 8; off <<= 1) {
    double ov = __shfl_xor(v1, off, 64);
    int oi = __shfl_xor(i1, off, 64);
    if (ov > v1 || (ov == v1 && oi < i1)) { v1 = ov; i1 = oi; }
  }
  // top-2
  double v2 = (e == i1) ? -1e300 : p; int i2 = e;
#pragma unroll
  for (int off = 1; off < 8; off <<= 1) {
    double ov = __shfl_xor(v2, off, 64);
    int oi = __shfl_xor(i2, off, 64);
    if (ov > v2 || (ov == v2 && oi < i2)) { v2 = ov; i2 = oi; }
  }
  if (e == 0 && half == 0) {
    double ev = exp(v2 - v1);
    double iw = 1.0 / (1.0 + ev);
    e1a[tok] = i1; e2a[tok] = i2;
    w1a[tok] = (float)iw; w2a[tok] = (float)(ev * iw);
    r1a[tok] = atomicAdd(&cnt[i1], 1);
    r2a[tok] = atomicAdd(&cnt[8 + i2], 1);
  }
  __syncthreads();
  if (tid < 16) hist[blockIdx.x * 16 + tid] = cnt[tid];
}

// ---------- scan: per-counter exclusive prefix over gate blocks + pad-fill toks ----------
__global__ __launch_bounds__(1024) void k_scan2(const int* __restrict__ hist,
                                                int* __restrict__ blockbase,
                                                int* __restrict__ aoff,
                                                int* __restrict__ counts,
                                                int* __restrict__ toks) {
  __shared__ int tot[16];
  __shared__ int s_ao[16];
  const int c = threadIdx.x >> 6;   // counter 0..15
  const int l = threadIdx.x & 63;
  int v[GBLK / 64];
  int s = 0;
#pragma unroll
  for (int j = 0; j < GBLK / 64; j++) {
    v[j] = hist[((l * (GBLK / 64) + j) << 4) + c];
    s += v[j];
  }
  int incl = s;
#pragma unroll
  for (int off = 1; off < 64; off <<= 1) {
    int t = __shfl_up(incl, off, 64);
    if (l >= off) incl += t;
  }
  int run = incl - s;  // exclusive
#pragma unroll
  for (int j = 0; j < GBLK / 64; j++) {
    blockbase[((l * (GBLK / 64) + j) << 4) + c] = run;
    run += v[j];
  }
  if (l == 63) tot[c] = incl;
  __syncthreads();
  if (threadIdx.x == 0) {
    int o0 = 0, o1 = 0;
    for (int e = 0; e < NEXP; e++) {
      counts[e] = tot[e];
      aoff[e] = o0; s_ao[e] = o0; o0 += (tot[e] + BM - 1) / BM * BM;
      counts[8 + e] = tot[8 + e];
      aoff[9 + e] = o1; s_ao[8 + e] = o1; o1 += (tot[8 + e] + BM - 1) / BM * BM;
    }
    aoff[8] = o0; aoff[17] = o1;
  }
  __syncthreads();
  // zero-fill pad slots so expert MODE 0 gathers a valid token index
  const int cnt_c = tot[c];
  const int padded = (cnt_c + BM - 1) / BM * BM;
  const int base = ((c >> 3) ? SLOTS : 0) + s_ao[c];
  for (int sidx = cnt_c + l; sidx < padded; sidx += 64)
    toks[base + sidx] = 0;
}

// ---------- scatter: slot = aoff + blockbase + rank (no atomics) ----------
__global__ void k_scatter2(const int* __restrict__ e1a, const int* __restrict__ e2a,
                           const float* __restrict__ w1a, const float* __restrict__ w2a,
                           const int* __restrict__ r1a, const int* __restrict__ r2a,
                           const int* __restrict__ blockbase, const int* __restrict__ aoff,
                           int* __restrict__ toks, float* __restrict__ wsl) {
  int n = blockIdx.x * 256 + threadIdx.x;
  int blk = n >> 4;
  int e1 = e1a[n];
  int slot = aoff[e1] + blockbase[(blk << 4) + e1] + r1a[n];
  toks[slot] = n; wsl[slot] = w1a[n];
  int e2 = e2a[n];
  slot = SLOTS + aoff[9 + e2] + blockbase[(blk << 4) + 8 + e2] + r2a[n];
  toks[slot] = n; wsl[slot] = w2a[n];
}

// ---------- expert GEMM: MODE 0 = layer1 (x->H, relu), 1 = layer2 k=0 (y=),
// 2 = layer2 k=1 (y+=) ----------
template <int MODE>
__global__ __launch_bounds__(256) void k_expert(
    const f16* __restrict__ Asrc, const f16* __restrict__ Wt,
    const float* __restrict__ bias, const int* __restrict__ toks,
    const float* __restrict__ wsl, const int* __restrict__ aoff,
    const int* __restrict__ counts, f16* __restrict__ Hout,
    float* __restrict__ y, int kpass) {
  const int klist = (MODE == 0) ? blockIdx.z : kpass;
  const int* ao = aoff + klist * 9;
  const int slot0 = blockIdx.x * BM;
  if (slot0 >= ao[8]) return;
  int e = 0;
#pragma unroll
  for (int t = 1; t <= 7; t++) if (slot0 >= ao[t]) e = t;

  const int n0 = blockIdx.y * BN;
  const int tid = threadIdx.x, lane = tid & 63, wid = tid >> 6;

  __shared__ __align__(16) f16 As[BM * BK];
  __shared__ __align__(16) f16 Bs[BN * BK];

  const int srow = wid * 16 + (lane >> 2);
  const int scol = (lane & 3) * 8;
  const f16* arow[2];
  const f16* brow[2];
  f16* alds[2];
  f16* blds[2];
#pragma unroll
  for (int rnd = 0; rnd < 2; rnd++) {
    int r = srow + rnd * 64;
    if (MODE == 0) {
      int tk = toks[klist * SLOTS + slot0 + r];
      arow[rnd] = Asrc + (size_t)tk * DIM + scol;
    } else {
      arow[rnd] = Asrc + (size_t)(klist * SLOTS + slot0 + r) * HIDN + scol;
    }
    brow[rnd] = Wt + ((size_t)e * DIM + n0 + r) * DIM + scol;
    alds[rnd] = As + (wid * 16 + rnd * 64) * BK;
    blds[rnd] = Bs + (wid * 16 + rnd * 64) * BK;
  }

  f32x4 acc[4][4] = {};
  const int wr = wid >> 1, wc = wid & 1;
  const int fr = lane & 15, kb = (lane >> 4) * 8;

  for (int ks = 0; ks < DIM; ks += BK) {
    __syncthreads();
#pragma unroll
    for (int rnd = 0; rnd < 2; rnd++) {
      gl2lds16(arow[rnd] + ks, alds[rnd]);
      gl2lds16(brow[rnd] + ks, blds[rnd]);
    }
    __syncthreads();
    f16x8 af[4], bf[4];
#pragma unroll
    for (int m = 0; m < 4; m++)
      af[m] = *(const f16x8*)(As + (wr * 64 + m * 16 + fr) * BK + kb);
#pragma unroll
    for (int n = 0; n < 4; n++)
      bf[n] = *(const f16x8*)(Bs + (wc * 64 + n * 16 + fr) * BK + kb);
#pragma unroll
    for (int m = 0; m < 4; m++)
#pragma unroll
      for (int n = 0; n < 4; n++)
        acc[m][n] = __builtin_amdgcn_mfma_f32_16x16x32_f16(af[m], bf[n], acc[m][n], 0, 0, 0);
  }

  float bcol[4];
#pragma unroll
  for (int n = 0; n < 4; n++) bcol[n] = bias[e * ((MODE == 0) ? HIDN : DIM) + n0 + wc * 64 + n * 16 + fr];

  if (MODE == 0) {
#pragma unroll
    for (int m = 0; m < 4; m++)
#pragma unroll
      for (int r4 = 0; r4 < 4; r4++) {
        int slot = slot0 + wr * 64 + m * 16 + (lane >> 4) * 4 + r4;
#pragma unroll
        for (int n = 0; n < 4; n++) {
          int col = n0 + wc * 64 + n * 16 + fr;
          float v = acc[m][n][r4] + bcol[n];
          Hout[(size_t)(klist * SLOTS + slot) * HIDN + col] = (f16)fmaxf(v, 0.f);
        }
      }
  } else {
    const int vend = ao[e] + counts[klist * 8 + e];
#pragma unroll
    for (int m = 0; m < 4; m++)
#pragma unroll
      for (int r4 = 0; r4 < 4; r4++) {
        int slot = slot0 + wr * 64 + m * 16 + (lane >> 4) * 4 + r4;
        if (slot < vend) {
          int tk = toks[klist * SLOTS + slot];
          float w = wsl[klist * SLOTS + slot];
#pragma unroll
          for (int n = 0; n < 4; n++) {
            int col = n0 + wc * 64 + n * 16 + fr;
            float v = (acc[m][n][r4] + bcol[n]) * w;
            size_t oi = (size_t)tk * DIM + col;
            if (MODE == 1) y[oi] = v;
            else y[oi] += v;
          }
        }
      }
  }
}

// ---------- importance loss ----------
__global__ void k_imploss(const float* __restrict__ gp, float* __restrict__ loss) {
  __shared__ double simp[256][8];
  __shared__ double colsum[8];
  double im[8] = {0, 0, 0, 0, 0, 0, 0, 0};
  for (int n = threadIdx.x; n < NTOK; n += 256) {
#pragma unroll
    for (int e = 0; e < 8; e++) im[e] += (double)gp[(size_t)n * 8 + e];
  }
#pragma unroll
  for (int e = 0; e < 8; e++) simp[threadIdx.x][e] = im[e];
  __syncthreads();
  if (threadIdx.x < 8) {
    double s = 0.0;
    for (int t = 0; t < 256; t++) s += simp[t][threadIdx.x];
    colsum[threadIdx.x] = s;
  }
  __syncthreads();
  if (threadIdx.x == 0) {
    double m = 0.0;
    for (int e = 0; e < 8; e++) m += colsum[e];
    m *= (1.0 / 8.0);
    double var = 0.0;
    for (int e = 0; e < 8; e++) { double d = colsum[e] - m; var += d * d; }
    var *= (1.0 / 7.0);
    double r = sqrt(var) / m;
    loss[0] = (float)(0.01 * r * r);
  }
}

extern "C" void kernel_launch(void* const* d_in, const int* in_sizes, int n_in,
                              void* d_out, int out_size, void* d_ws, size_t ws_size,
                              hipStream_t stream) {
  const float* x  = (const float*)d_in[0];
  const float* q  = (const float*)d_in[1];
  const float* Wv = (const float*)d_in[6];
  const float* bv = (const float*)d_in[7];
  const float* Wo = (const float*)d_in[8];
  const float* bo = (const float*)d_in[9];
  const float* gW = (const float*)d_in[10];
  const float* gb = (const float*)d_in[11];
  const float* W1 = (const float*)d_in[12];
  const float* b1 = (const float*)d_in[13];
  const float* W2 = (const float*)d_in[14];
  const float* b2 = (const float*)d_in[15];

  float* out = (float*)d_out;
  float* y_out = out;
  float* gp_out = out + (size_t)NTOK * DIM;
  float* loss_out = gp_out + (size_t)NTOK * NEXP;

  uint8_t* w = (uint8_t*)d_ws;
  size_t o = 0;
  auto alloc = [&](size_t bytes) -> void* {
    void* p = w + o;
    o = (o + bytes + 255) & ~(size_t)255;
    return p;
  };
  f16* xh      = (f16*)alloc((size_t)NTOK * DIM * 2);
  f16* W1t     = (f16*)alloc((size_t)NEXP * DIM * HIDN * 2);
  f16* W2t     = (f16*)alloc((size_t)NEXP * DIM * HIDN * 2);
  f16* Hbuf    = (f16*)alloc((size_t)2 * SLOTS * HIDN * 2);
  double* G1   = (double*)alloc((size_t)DIM * NEXP * 8);
  float* Wg    = (float*)alloc((size_t)DIM * NEXP * 4);
  double* bg   = (double*)alloc(NEXP * 8);
  int* e1a     = (int*)alloc(NTOK * 4);
  int* e2a     = (int*)alloc(NTOK * 4);
  float* w1a   = (float*)alloc(NTOK * 4);
  float* w2a   = (float*)alloc(NTOK * 4);
  int* r1a     = (int*)alloc(NTOK * 4);
  int* r2a     = (int*)alloc(NTOK * 4);
  int* hist    = (int*)alloc((size_t)GBLK * 16 * 4);
  int* bbase   = (int*)alloc((size_t)GBLK * 16 * 4);
  int* counts  = (int*)alloc(16 * 4);
  int* aoff    = (int*)alloc(18 * 4);
  int* toks    = (int*)alloc((size_t)2 * SLOTS * 4);
  float* wsl   = (float*)alloc((size_t)2 * SLOTS * 4);
  (void)ws_size; (void)in_sizes; (void)n_in; (void)out_size;

  k_conv_x<<<(NTOK * DIM / 4 + 255) / 256, 256, 0, stream>>>(x, xh);
  k_transpose_cast2<<<dim3(16, 16, 16), 256, 0, stream>>>(W1, W2, W1t, W2t);
  k_foldA<<<1024, 256, 0, stream>>>(Wo, gW, G1);
  k_foldB<<<1025, 256, 0, stream>>>(Wv, G1, Wg, bv, bo, gW, gb, bg);
  k_gate<<<GBLK, 256, 0, stream>>>(q, Wg, bg, gp_out, e1a, e2a, w1a, w2a, r1a, r2a, hist);
  k_scan2<<<1, 1024, 0, stream>>>(hist, bbase, aoff, counts, toks);
  k_scatter2<<<NTOK / 256, 256, 0, stream>>>(e1a, e2a, w1a, w2a, r1a, r2a, bbase, aoff, toks, wsl);
  k_expert<0><<<dim3(MAXRB, 4, 2), 256, 0, stream>>>(xh, W1t, b1, toks, wsl, aoff, counts,
                                                     Hbuf, nullptr, 0);
  k_expert<1><<<dim3(MAXRB, 4, 1), 256, 0, stream>>>(Hbuf, W2t, b2, toks, wsl, aoff, counts,
                                                     nullptr, y_out, 0);
  k_expert<2><<<dim3(MAXRB, 4, 1), 256, 0, stream>>>(Hbuf, W2t, b2, toks, wsl, aoff, counts,
                                                     nullptr, y_out, 1);
  k_imploss<<<1, 256, 0, stream>>>(gp_out, loss_out);
}

// Round 5
// 114.288 us; speedup vs baseline: 3.3386x; 1.1533x over previous
//
#include <hip/hip_runtime.h>
#include <math.h>
#include <stdint.h>

#define NTOK 8192
#define DIM  512
#define NEXP 8
#define HIDN 512
#define BM 128
#define BN 128
#define BK 32
#define NT  (DIM / BK)        // 16 K-steps
#define MAXRB 72              // ceil((8192 + 8*127)/128)
#define SLOTS (MAXRB*BM)      // 9216
#define GBLK (NTOK/16)        // 512 gate blocks (16 tokens each)

typedef _Float16 f16;
typedef __attribute__((ext_vector_type(4))) _Float16 f16x4;
typedef __attribute__((ext_vector_type(8))) _Float16 f16x8;
typedef __attribute__((ext_vector_type(4))) float    f32x4;

__device__ __forceinline__ void gl2lds16(const void* g, void* l) {
  __builtin_amdgcn_global_load_lds(
      (const __attribute__((address_space(1))) unsigned int*)(g),
      (__attribute__((address_space(3))) unsigned int*)(l), 16, 0, 0);
}

// ---------- prep: x->f16 | W1/W2 transpose-cast | zero y ----------
__global__ __launch_bounds__(256) void k_prep(
    const float* __restrict__ x, f16* __restrict__ xh,
    const float* __restrict__ W1, const float* __restrict__ W2,
    f16* __restrict__ W1t, f16* __restrict__ W2t, float* __restrict__ y) {
  const int bx = blockIdx.x, tid = threadIdx.x;
  if (bx < 4096) {               // x convert
    int i4 = (bx * 256 + tid) * 4;
    float4 v = *(const float4*)(x + i4);
    f16x4 o; o.x = (_Float16)v.x; o.y = (_Float16)v.y; o.z = (_Float16)v.z; o.w = (_Float16)v.w;
    *(f16x4*)(xh + i4) = o;
  } else if (bx < 8192) {        // weight transpose-cast
    __shared__ float t[32][33];
    int idx = bx - 4096;
    int z = idx >> 8, rem = idx & 255;
    int k0 = (rem >> 4) * 32, n0 = (rem & 15) * 32;
    const float* src = (z < 8 ? W1 : W2) + (size_t)(z & 7) * DIM * DIM;
    f16* dst = (z < 8 ? W1t : W2t) + (size_t)(z & 7) * DIM * DIM;
    int tx = tid & 31, ty = tid >> 5;
    for (int r = ty; r < 32; r += 8) t[r][tx] = src[(size_t)(k0 + r) * DIM + n0 + tx];
    __syncthreads();
    for (int r = ty; r < 32; r += 8) dst[(size_t)(n0 + r) * DIM + k0 + tx] = (f16)t[tx][r];
  } else {                       // zero y (16 MB)
    int b = bx - 8192;
    float4 z4 = {0.f, 0.f, 0.f, 0.f};
#pragma unroll
    for (int it = 0; it < 4; it++)
      *(float4*)(y + (size_t)b * 4096 + it * 1024 + tid * 4) = z4;
  }
}

// ---------- fp64 gate fold: Wg = Wv @ (Wo @ gate_W), bg folded ----------
__global__ void k_foldA(const float* __restrict__ Wo, const float* __restrict__ gW,
                        double* __restrict__ G1) {
  int out = blockIdx.x * 4 + (threadIdx.x >> 6);
  int lane = threadIdx.x & 63;
  int d = out >> 3, e = out & 7;
  double acc = 0.0;
#pragma unroll
  for (int j = 0; j < 8; j++) {
    int k = j * 64 + lane;
    acc += (double)Wo[d * DIM + k] * (double)gW[k * NEXP + e];
  }
#pragma unroll
  for (int off = 32; off; off >>= 1) acc += __shfl_xor(acc, off, 64);
  if (lane == 0) G1[out] = acc;
}

// blocks 0..1023: Wg = fp32(Wv @ G1). block 1024: bg fold.
__global__ void k_foldB(const float* __restrict__ Wv, const double* __restrict__ G1,
                        float* __restrict__ Wg, const float* __restrict__ bv,
                        const float* __restrict__ bo, const float* __restrict__ gW,
                        const float* __restrict__ gb, double* __restrict__ bg) {
  int lane = threadIdx.x & 63;
  if (blockIdx.x == 1024) {
    int w = threadIdx.x >> 6;
    for (int e = w; e < NEXP; e += 4) {
      double acc = 0.0;
#pragma unroll
      for (int j = 0; j < 8; j++) {
        int d = j * 64 + lane;
        acc += (double)bv[d] * G1[d * NEXP + e] + (double)bo[d] * (double)gW[d * NEXP + e];
      }
#pragma unroll
      for (int off = 32; off; off >>= 1) acc += __shfl_xor(acc, off, 64);
      if (lane == 0) bg[e] = acc + (double)gb[e];
    }
    return;
  }
  int out = blockIdx.x * 4 + (threadIdx.x >> 6);
  int d = out >> 3, e = out & 7;
  double acc = 0.0;
#pragma unroll
  for (int j = 0; j < 8; j++) {
    int k = j * 64 + lane;
    acc += (double)Wv[d * DIM + k] * G1[k * NEXP + e];
  }
#pragma unroll
  for (int off = 32; off; off >>= 1) acc += __shfl_xor(acc, off, 64);
  if (lane == 0) Wg[out] = (float)acc;
}

// ---------- gate: thread-per-(token,expert,half). fp64 logits (routing parity
// with R4), fp32 softmax/top-w. Emits per-block hist + ranks + gp block-sums.
__global__ __launch_bounds__(256) void k_gate(
    const float* __restrict__ q, const float* __restrict__ Wg,
    const double* __restrict__ bg, float* __restrict__ gp_out,
    int* __restrict__ e1a, int* __restrict__ e2a,
    float* __restrict__ w1a, float* __restrict__ w2a,
    int* __restrict__ r1a, int* __restrict__ r2a, int* __restrict__ hist,
    float* __restrict__ gpsum) {
  __shared__ float qs[16 * 513];
  __shared__ float ps[16][8];
  __shared__ int cnt[16];
  const int tid = threadIdx.x;
  const int tok0 = blockIdx.x * 16;

  for (int i = tid; i < 16 * 512; i += 256) {
    int r = i >> 9, c = i & 511;
    qs[r * 513 + c] = q[(size_t)(tok0 + r) * DIM + c];
  }
  if (tid < 16) cnt[tid] = 0;
  __syncthreads();

  const int e = tid & 7;
  const int half = (tid >> 3) & 1;
  const int tl = tid >> 4;
  const float* qrow = qs + tl * 513 + half * 256;
  const float* wcol = Wg + half * 256 * NEXP + e;

  double a0 = 0, a1 = 0, a2 = 0, a3 = 0;
#pragma unroll 4
  for (int j = 0; j < 256; j += 4) {
    a0 += (double)qrow[j]     * (double)wcol[(size_t)j * NEXP];
    a1 += (double)qrow[j + 1] * (double)wcol[(size_t)(j + 1) * NEXP];
    a2 += (double)qrow[j + 2] * (double)wcol[(size_t)(j + 2) * NEXP];
    a3 += (double)qrow[j + 3] * (double)wcol[(size_t)(j + 3) * NEXP];
  }
  double acc = (a0 + a1) + (a2 + a3);
  acc += __shfl_xor(acc, 8, 64);  // combine halves

  double l = acc + bg[e];
  double m = l;
#pragma unroll
  for (int off = 1; off < 8; off <<= 1) m = fmax(m, __shfl_xor(m, off, 64));
  float ex = expf((float)(l - m));
  float s = ex;
#pragma unroll
  for (int off = 1; off < 8; off <<= 1) s += __shfl_xor(s, off, 64);
  float pf = ex / s;
  int tok = tok0 + tl;
  if (half == 0) { gp_out[(size_t)tok * NEXP + e] = pf; ps[tl][e] = pf; }

  // top-1/top-2 ordered by fp64 logit (monotone == prob ordering)
  double v1 = l; int i1 = e;
#pragma unroll
  for (int off = 1; off < 8; off <<= 1) {
    double ov = __shfl_xor(v1, off, 64);
    int oi = __shfl_xor(i1, off, 64);
    if (ov > v1 || (ov == v1 && oi < i1)) { v1 = ov; i1 = oi; }
  }
  double v2 = (e == i1) ? -1e300 : l; int i2 = e;
#pragma unroll
  for (int off = 1; off < 8; off <<= 1) {
    double ov = __shfl_xor(v2, off, 64);
    int oi = __shfl_xor(i2, off, 64);
    if (ov > v2 || (ov == v2 && oi < i2)) { v2 = ov; i2 = oi; }
  }
  float p1 = __shfl(pf, (tl << 4) + i1, 64);
  float p2 = __shfl(pf, (tl << 4) + i2, 64);
  if (e == 0 && half == 0) {
    float ev = expf(p2 - p1);
    float iw = 1.0f / (1.0f + ev);
    e1a[tok] = i1; e2a[tok] = i2;
    w1a[tok] = iw; w2a[tok] = ev * iw;
    r1a[tok] = atomicAdd(&cnt[i1], 1);
    r2a[tok] = atomicAdd(&cnt[8 + i2], 1);
  }
  __syncthreads();
  if (tid < 16) hist[blockIdx.x * 16 + tid] = cnt[tid];
  if (tid < 8) {
    float ssum = 0.f;
#pragma unroll
    for (int r = 0; r < 16; r++) ssum += ps[r][tid];
    gpsum[blockIdx.x * 8 + tid] = ssum;
  }
}

// ---------- scan: prefix over gate blocks + pad-fill toks + importance loss ----------
__global__ __launch_bounds__(1024) void k_scan2(const int* __restrict__ hist,
                                                int* __restrict__ blockbase,
                                                int* __restrict__ aoff,
                                                int* __restrict__ counts,
                                                int* __restrict__ toks,
                                                const float* __restrict__ gpsum,
                                                float* __restrict__ loss) {
  __shared__ int tot[16];
  __shared__ int s_ao[16];
  __shared__ double imp[8];
  const int c = threadIdx.x >> 6;   // counter 0..15
  const int l = threadIdx.x & 63;
  int v[GBLK / 64];
  int s = 0;
#pragma unroll
  for (int j = 0; j < GBLK / 64; j++) {
    v[j] = hist[((l * (GBLK / 64) + j) << 4) + c];
    s += v[j];
  }
  int incl = s;
#pragma unroll
  for (int off = 1; off < 64; off <<= 1) {
    int t = __shfl_up(incl, off, 64);
    if (l >= off) incl += t;
  }
  int run = incl - s;  // exclusive
#pragma unroll
  for (int j = 0; j < GBLK / 64; j++) {
    blockbase[((l * (GBLK / 64) + j) << 4) + c] = run;
    run += v[j];
  }
  if (l == 63) tot[c] = incl;
  __syncthreads();
  if (threadIdx.x == 0) {
    int o0 = 0, o1 = 0;
    for (int e = 0; e < NEXP; e++) {
      counts[e] = tot[e];
      aoff[e] = o0; s_ao[e] = o0; o0 += (tot[e] + BM - 1) / BM * BM;
      counts[8 + e] = tot[8 + e];
      aoff[9 + e] = o1; s_ao[8 + e] = o1; o1 += (tot[8 + e] + BM - 1) / BM * BM;
    }
    aoff[8] = o0; aoff[17] = o1;
  }
  __syncthreads();
  // zero-fill pad slots so expert MODE 0 gathers a valid token index
  const int cnt_c = tot[c];
  const int padded = (cnt_c + BM - 1) / BM * BM;
  const int base = ((c >> 3) ? SLOTS : 0) + s_ao[c];
  for (int sidx = cnt_c + l; sidx < padded; sidx += 64)
    toks[base + sidx] = 0;
  // importance loss: imp[e] = sum over 512 block-sums (fp64)
  if (c < 8) {
    double a = 0.0;
#pragma unroll
    for (int j = 0; j < GBLK / 64; j++)
      a += (double)gpsum[(size_t)(l + j * 64) * 8 + c];
#pragma unroll
    for (int off = 32; off; off >>= 1) a += __shfl_xor(a, off, 64);
    if (l == 0) imp[c] = a;
  }
  __syncthreads();
  if (threadIdx.x == 0) {
    double mn = 0.0;
    for (int e = 0; e < 8; e++) mn += imp[e];
    mn *= (1.0 / 8.0);
    double var = 0.0;
    for (int e = 0; e < 8; e++) { double d = imp[e] - mn; var += d * d; }
    var *= (1.0 / 7.0);
    double r = sqrt(var) / mn;
    loss[0] = (float)(0.01 * r * r);
  }
}

// ---------- scatter: slot = aoff + blockbase + rank (no atomics) ----------
__global__ void k_scatter2(const int* __restrict__ e1a, const int* __restrict__ e2a,
                           const float* __restrict__ w1a, const float* __restrict__ w2a,
                           const int* __restrict__ r1a, const int* __restrict__ r2a,
                           const int* __restrict__ blockbase, const int* __restrict__ aoff,
                           int* __restrict__ toks, float* __restrict__ wsl) {
  int n = blockIdx.x * 256 + threadIdx.x;
  int blk = n >> 4;
  int e1 = e1a[n];
  int slot = aoff[e1] + blockbase[(blk << 4) + e1] + r1a[n];
  toks[slot] = n; wsl[slot] = w1a[n];
  int e2 = e2a[n];
  slot = SLOTS + aoff[9 + e2] + blockbase[(blk << 4) + 8 + e2] + r2a[n];
  toks[slot] = n; wsl[slot] = w2a[n];
}

// ---------- expert GEMM, 2-phase double-buffered pipeline ----------
// MODE 0: layer1 (x->H, relu). MODE 1: layer2, y += w*(h@W2+b2) via atomics.
template <int MODE>
__global__ __launch_bounds__(256) void k_expert(
    const f16* __restrict__ Asrc, const f16* __restrict__ Wt,
    const float* __restrict__ bias, const int* __restrict__ toks,
    const float* __restrict__ wsl, const int* __restrict__ aoff,
    const int* __restrict__ counts, f16* __restrict__ Hout,
    float* __restrict__ y) {
  const int klist = blockIdx.z;
  const int* ao = aoff + klist * 9;
  const int slot0 = blockIdx.x * BM;
  if (slot0 >= ao[8]) return;
  int e = 0;
#pragma unroll
  for (int t = 1; t <= 7; t++) if (slot0 >= ao[t]) e = t;

  const int n0 = blockIdx.y * BN;
  const int tid = threadIdx.x, lane = tid & 63, wid = tid >> 6;

  __shared__ __align__(16) f16 As[2][BM * BK];
  __shared__ __align__(16) f16 Bs[2][BN * BK];

  const int srow = wid * 16 + (lane >> 2);
  const int scol = (lane & 3) * 8;
  const f16* arow[2];
  const f16* brow[2];
  int loff[2];
#pragma unroll
  for (int rnd = 0; rnd < 2; rnd++) {
    int r = srow + rnd * 64;
    if (MODE == 0) {
      int tk = toks[klist * SLOTS + slot0 + r];
      arow[rnd] = Asrc + (size_t)tk * DIM + scol;
    } else {
      arow[rnd] = Asrc + (size_t)(klist * SLOTS + slot0 + r) * HIDN + scol;
    }
    brow[rnd] = Wt + ((size_t)e * DIM + n0 + r) * DIM + scol;
    loff[rnd] = (wid * 16 + rnd * 64) * BK;
  }

  f32x4 acc[4][4] = {};
  const int wr = wid >> 1, wc = wid & 1;
  const int fr = lane & 15, kb = (lane >> 4) * 8;

#define STAGE(buf, ks)                                  \
  {                                                     \
    _Pragma("unroll")                                   \
    for (int rnd = 0; rnd < 2; rnd++) {                 \
      gl2lds16(arow[rnd] + (ks), As[buf] + loff[rnd]);  \
      gl2lds16(brow[rnd] + (ks), Bs[buf] + loff[rnd]);  \
    }                                                   \
  }

  STAGE(0, 0);
#pragma unroll
  for (int t = 0; t < NT; t++) {
    const int cur = t & 1;
    if (t + 1 < NT) {
      STAGE(cur ^ 1, (t + 1) * BK);
      asm volatile("s_waitcnt vmcnt(4)" ::: "memory");
    } else {
      asm volatile("s_waitcnt vmcnt(0)" ::: "memory");
    }
    __builtin_amdgcn_s_barrier();
    f16x8 af[4], bf[4];
#pragma unroll
    for (int m = 0; m < 4; m++)
      af[m] = *(const f16x8*)(As[cur] + (wr * 64 + m * 16 + fr) * BK + kb);
#pragma unroll
    for (int n = 0; n < 4; n++)
      bf[n] = *(const f16x8*)(Bs[cur] + (wc * 64 + n * 16 + fr) * BK + kb);
#pragma unroll
    for (int m = 0; m < 4; m++)
#pragma unroll
      for (int n = 0; n < 4; n++)
        acc[m][n] = __builtin_amdgcn_mfma_f32_16x16x32_f16(af[m], bf[n], acc[m][n], 0, 0, 0);
    __builtin_amdgcn_s_barrier();
  }
#undef STAGE

  float bcol[4];
#pragma unroll
  for (int n = 0; n < 4; n++)
    bcol[n] = bias[e * ((MODE == 0) ? HIDN : DIM) + n0 + wc * 64 + n * 16 + fr];

  if (MODE == 0) {
#pragma unroll
    for (int m = 0; m < 4; m++)
#pragma unroll
      for (int r4 = 0; r4 < 4; r4++) {
        int slot = slot0 + wr * 64 + m * 16 + (lane >> 4) * 4 + r4;
#pragma unroll
        for (int n = 0; n < 4; n++) {
          int col = n0 + wc * 64 + n * 16 + fr;
          float v = acc[m][n][r4] + bcol[n];
          Hout[(size_t)(klist * SLOTS + slot) * HIDN + col] = (f16)fmaxf(v, 0.f);
        }
      }
  } else {
    const int vend = ao[e] + counts[klist * 8 + e];
#pragma unroll
    for (int m = 0; m < 4; m++)
#pragma unroll
      for (int r4 = 0; r4 < 4; r4++) {
        int slot = slot0 + wr * 64 + m * 16 + (lane >> 4) * 4 + r4;
        if (slot < vend) {
          int tk = toks[klist * SLOTS + slot];
          float w = wsl[klist * SLOTS + slot];
#pragma unroll
          for (int n = 0; n < 4; n++) {
            int col = n0 + wc * 64 + n * 16 + fr;
            float v = (acc[m][n][r4] + bcol[n]) * w;
            // exactly 2 adds per element (k0,k1) on a zeroed buffer:
            // 2-operand fp add is commutative -> bitwise deterministic
            __hip_atomic_fetch_add(&y[(size_t)tk * DIM + col], v,
                                   __ATOMIC_RELAXED, __HIP_MEMORY_SCOPE_AGENT);
          }
        }
      }
  }
}

extern "C" void kernel_launch(void* const* d_in, const int* in_sizes, int n_in,
                              void* d_out, int out_size, void* d_ws, size_t ws_size,
                              hipStream_t stream) {
  const float* x  = (const float*)d_in[0];
  const float* q  = (const float*)d_in[1];
  const float* Wv = (const float*)d_in[6];
  const float* bv = (const float*)d_in[7];
  const float* Wo = (const float*)d_in[8];
  const float* bo = (const float*)d_in[9];
  const float* gW = (const float*)d_in[10];
  const float* gb = (const float*)d_in[11];
  const float* W1 = (const float*)d_in[12];
  const float* b1 = (const float*)d_in[13];
  const float* W2 = (const float*)d_in[14];
  const float* b2 = (const float*)d_in[15];

  float* out = (float*)d_out;
  float* y_out = out;
  float* gp_out = out + (size_t)NTOK * DIM;
  float* loss_out = gp_out + (size_t)NTOK * NEXP;

  uint8_t* w = (uint8_t*)d_ws;
  size_t o = 0;
  auto alloc = [&](size_t bytes) -> void* {
    void* p = w + o;
    o = (o + bytes + 255) & ~(size_t)255;
    return p;
  };
  f16* xh      = (f16*)alloc((size_t)NTOK * DIM * 2);
  f16* W1t     = (f16*)alloc((size_t)NEXP * DIM * HIDN * 2);
  f16* W2t     = (f16*)alloc((size_t)NEXP * DIM * HIDN * 2);
  f16* Hbuf    = (f16*)alloc((size_t)2 * SLOTS * HIDN * 2);
  double* G1   = (double*)alloc((size_t)DIM * NEXP * 8);
  float* Wg    = (float*)alloc((size_t)DIM * NEXP * 4);
  double* bg   = (double*)alloc(NEXP * 8);
  int* e1a     = (int*)alloc(NTOK * 4);
  int* e2a     = (int*)alloc(NTOK * 4);
  float* w1a   = (float*)alloc(NTOK * 4);
  float* w2a   = (float*)alloc(NTOK * 4);
  int* r1a     = (int*)alloc(NTOK * 4);
  int* r2a     = (int*)alloc(NTOK * 4);
  int* hist    = (int*)alloc((size_t)GBLK * 16 * 4);
  int* bbase   = (int*)alloc((size_t)GBLK * 16 * 4);
  float* gpsum = (float*)alloc((size_t)GBLK * 8 * 4);
  int* counts  = (int*)alloc(16 * 4);
  int* aoff    = (int*)alloc(18 * 4);
  int* toks    = (int*)alloc((size_t)2 * SLOTS * 4);
  float* wsl   = (float*)alloc((size_t)2 * SLOTS * 4);
  (void)ws_size; (void)in_sizes; (void)n_in; (void)out_size;

  k_prep<<<9216, 256, 0, stream>>>(x, xh, W1, W2, W1t, W2t, y_out);
  k_foldA<<<1024, 256, 0, stream>>>(Wo, gW, G1);
  k_foldB<<<1025, 256, 0, stream>>>(Wv, G1, Wg, bv, bo, gW, gb, bg);
  k_gate<<<GBLK, 256, 0, stream>>>(q, Wg, bg, gp_out, e1a, e2a, w1a, w2a, r1a, r2a, hist, gpsum);
  k_scan2<<<1, 1024, 0, stream>>>(hist, bbase, aoff, counts, toks, gpsum, loss_out);
  k_scatter2<<<NTOK / 256, 256, 0, stream>>>(e1a, e2a, w1a, w2a, r1a, r2a, bbase, aoff, toks, wsl);
  k_expert<0><<<dim3(MAXRB, 4, 2), 256, 0, stream>>>(xh, W1t, b1, toks, wsl, aoff, counts,
                                                     Hbuf, nullptr);
  k_expert<1><<<dim3(MAXRB, 4, 2), 256, 0, stream>>>(Hbuf, W2t, b2, toks, wsl, aoff, counts,
                                                     nullptr, y_out);
}